// Round 9
// baseline (775.715 us; speedup 1.0000x reference)
//
#include <hip/hip_runtime.h>
#include <hip/hip_bf16.h>

#define NNODES 100000
#define NEDGES 3200000
#define NG     64
#define NBUCK  196          // ceil(NNODES/512) buckets of 512 dst nodes
#define PB     256          // phase-A partition blocks
#define SCAN_M (PB * NBUCK) // 50176
#define SCAN_NB ((SCAN_M + 1023) / 1024)   // 49

// ---------- dtype-flexible loads (flags are wave-uniform) ----------
__device__ __forceinline__ int ld_idx(const void* p, long long i, int is64) {
    if (is64) return (int)((const long long*)p)[i];
    return ((const int*)p)[i];
}
__device__ __forceinline__ float ld_f(const void* p, long long i, int isf32) {
    if (isf32) return ((const float*)p)[i];
    return __bfloat162float(((const __hip_bfloat16*)p)[i]);
}
__device__ __forceinline__ float bfbits(unsigned b) {
    return __uint_as_float(b << 16);
}

// ---------- runtime dtype detection (parallel, 256 threads) ----------
__global__ void detect_kernel(const void* x, const void* ei, const void* bat, int* flags) {
    __shared__ int f[3];
    int t = threadIdx.x;
    if (t < 3) f[t] = 0;
    __syncthreads();
    const unsigned short* u = (const unsigned short*)x;
    int e = (u[t] >> 7) & 0xFF;
    if (e >= 0x90) atomicOr(&f[0], 1);                 // fp32-reinterpret signature
    const unsigned* w = (const unsigned*)ei;
    if (w[2 * t + 1] != 0u) atomicOr(&f[1], 1);        // odd word nonzero -> int32
    const unsigned* bw = (const unsigned*)bat;
    if (bw[50001 + 2 * t] != 0u) atomicOr(&f[2], 1);   // mid-array odd words
    __syncthreads();
    if (t == 0) { flags[0] = f[0]; flags[1] = !f[1]; flags[2] = !f[2]; }
}

// ---------- phase A1: per-(bucket,block) edge counts (LDS only) ----------
__global__ void binA_count(const void* ei, const int* __restrict__ flags,
                           int* __restrict__ bcnt, int E) {
    __shared__ int cnt[NBUCK];
    int is64 = flags[1];
    for (int i = threadIdx.x; i < NBUCK; i += 256) cnt[i] = 0;
    __syncthreads();
    const int chunk = (E + PB - 1) / PB;
    int beg = blockIdx.x * chunk, end = min(E, beg + chunk);
    for (int i = beg + threadIdx.x; i < end; i += 256) {
        int s = ld_idx(ei, i, is64);
        int d = ld_idx(ei, (long long)E + i, is64);
        if ((unsigned)s < (unsigned)NNODES && (unsigned)d < (unsigned)NNODES)
            atomicAdd(&cnt[d >> 9], 1);
    }
    __syncthreads();
    for (int i = threadIdx.x; i < NBUCK; i += 256)
        bcnt[i * PB + blockIdx.x] = cnt[i];     // bucket-major for scan
}

// ---------- parallel 3-phase exclusive scan over bcnt[SCAN_M] ----------
__global__ void scanP1(int* __restrict__ a, int* __restrict__ sums) {
    __shared__ int ls[1024];
    int t = threadIdx.x;
    int i = blockIdx.x * 1024 + t;
    int v = (i < SCAN_M) ? a[i] : 0;
    ls[t] = v;
    __syncthreads();
    for (int off = 1; off < 1024; off <<= 1) {
        int p = (t >= off) ? ls[t - off] : 0;
        __syncthreads();
        ls[t] += p;
        __syncthreads();
    }
    if (i < SCAN_M) a[i] = ls[t] - v;           // exclusive within block
    if (t == 1023) sums[blockIdx.x] = ls[1023]; // block total
}

__global__ void scanP2(int* __restrict__ sums) {
    __shared__ int ls[SCAN_NB];
    int t = threadIdx.x;
    if (t < SCAN_NB) ls[t] = sums[t];
    __syncthreads();
    if (t == 0) {
        int run = 0;
        for (int i = 0; i < SCAN_NB; ++i) { int c = ls[i]; ls[i] = run; run += c; }
        sums[SCAN_NB] = run;                    // grand total
    }
    __syncthreads();
    if (t < SCAN_NB) sums[t] = ls[t];
}

__global__ void scanP3(int* __restrict__ a, const int* __restrict__ sums) {
    int i = blockIdx.x * 1024 + threadIdx.x;
    if (i < SCAN_M) a[i] += sums[blockIdx.x];
    if (i == 0) a[SCAN_M] = sums[SCAN_NB];      // bcnt[M] = total
}

// ---------- phase A3: partition edges into bucket-ordered packed staging ----------
// pack: s (17 bits) | (d - bucket_lo) << 17  (9 bits) -> 4 B per edge
__global__ void binA_write(const void* ei, const int* __restrict__ flags,
                           const int* __restrict__ bcnt, unsigned* __restrict__ staging, int E) {
    __shared__ int cur[NBUCK];
    int is64 = flags[1];
    for (int i = threadIdx.x; i < NBUCK; i += 256) cur[i] = bcnt[i * PB + blockIdx.x];
    __syncthreads();
    const int chunk = (E + PB - 1) / PB;
    int beg = blockIdx.x * chunk, end = min(E, beg + chunk);
    for (int i = beg + threadIdx.x; i < end; i += 256) {
        int s = ld_idx(ei, i, is64);
        int d = ld_idx(ei, (long long)E + i, is64);
        if ((unsigned)s < (unsigned)NNODES && (unsigned)d < (unsigned)NNODES) {
            int pos = atomicAdd(&cur[d >> 9], 1);
            staging[pos] = (unsigned)s | ((unsigned)(d & 511) << 17);
        }
    }
}

// ---------- phase B1 (fused): per-bucket degrees -> rs (local scan + bucket base) + dinv ----------
__global__ void binB_deg_rs(const unsigned* __restrict__ staging, const int* __restrict__ bcnt,
                            int* __restrict__ rs, float* __restrict__ dinv) {
    __shared__ int dcnt[512];
    __shared__ int ls[256];
    int b = blockIdx.x;
    int lo = b << 9;
    int t = threadIdx.x;
    for (int i = t; i < 512; i += 256) dcnt[i] = 0;
    __syncthreads();
    int beg = bcnt[b * PB], end = bcnt[(b + 1) * PB];
    for (int i = beg + t; i < end; i += 256)
        atomicAdd(&dcnt[staging[i] >> 17], 1);
    __syncthreads();
    int a  = dcnt[2 * t];
    int b2 = dcnt[2 * t + 1];
    int csum = a + b2;
    ls[t] = csum;
    __syncthreads();
    for (int off = 1; off < 256; off <<= 1) {
        int p = (t >= off) ? ls[t - off] : 0;
        __syncthreads();
        ls[t] += p;
        __syncthreads();
    }
    int pref = ls[t] - csum;                    // exclusive prefix of this 2-chunk
    int n0 = lo + 2 * t, n1 = lo + 2 * t + 1;
    if (n0 < NNODES) { rs[n0] = beg + pref;     dinv[n0] = rsqrtf((float)a + 1.0f); }
    if (n1 < NNODES) { rs[n1] = beg + pref + a; dinv[n1] = rsqrtf((float)b2 + 1.0f); }
    if (b == NBUCK - 1 && t == 0) rs[NNODES] = bcnt[SCAN_M];
}

// ---------- phase B2: per-bucket CSR fill (LDS cursors; dense write regions) ----------
__global__ void binB_fill(const unsigned* __restrict__ staging, const int* __restrict__ bcnt,
                          const int* __restrict__ rs, int* __restrict__ csr) {
    __shared__ int cur[512];
    int b = blockIdx.x;
    int lo = b << 9;
    for (int i = threadIdx.x; i < 512; i += 256)
        cur[i] = (lo + i < NNODES) ? rs[lo + i] : 0;
    __syncthreads();
    int beg = bcnt[b * PB], end = bcnt[(b + 1) * PB];
    for (int i = beg + threadIdx.x; i < end; i += 256) {
        unsigned u = staging[i];
        int pos = atomicAdd(&cur[u >> 17], 1);
        csr[pos] = (int)(u & 0x1FFFFu);
    }
}

// ---------- GEMM: X-tile (64 rows) + W staged in LDS; spill-proof (round-7 proven) ----------
// XMODE 0: X has detected dtype; 1: fp32 workspace; 2: bf16 workspace.
// OUTBF 0: fp32 out; 1: bf16 out.
template <int K, int XMODE, int OUTBF>
__global__ __launch_bounds__(256)
void gemm_tile(const void* __restrict__ X, const void* __restrict__ W,
               const int* __restrict__ flags, const float* __restrict__ dscale,
               void* __restrict__ Out, int N) {
    __shared__ float lsW[K * 64];     // [k][c]
    __shared__ float lsX[64 * K];     // [r][k], fp32 after conversion
    int isf32 = flags[0];
    for (int i = threadIdx.x; i < K * 64; i += 256) lsW[i] = ld_f(W, i, isf32);

    int c  = threadIdx.x & 63;
    int wv = threadIdx.x >> 6;        // wave owns rows [wv*16, wv*16+16)
    int ntiles = (N + 63) >> 6;

    for (int t = blockIdx.x; t < ntiles; t += gridDim.x) {
        int row0 = t << 6;
        int nrows = min(64, N - row0);
        int total = nrows * K;
        __syncthreads();              // prev-tile readers done (also covers lsW on 1st iter)
        if (XMODE == 1 || (XMODE == 0 && isf32)) {
            const float* Xb = (const float*)X + (long long)row0 * K;
            for (int i = threadIdx.x; i < total; i += 256) lsX[i] = Xb[i];
        } else {
            const unsigned short* Xb = (const unsigned short*)X + (long long)row0 * K;
            for (int i = threadIdx.x; i < total; i += 256) lsX[i] = bfbits((unsigned)Xb[i]);
        }
        __syncthreads();

        int rbase = wv * 16;
        float acc[16];
#pragma unroll
        for (int r = 0; r < 16; ++r) acc[r] = 0.f;
#pragma unroll 1
        for (int kc = 0; kc < K; kc += 8) {
            float w0 = lsW[(kc + 0) * 64 + c], w1 = lsW[(kc + 1) * 64 + c];
            float w2 = lsW[(kc + 2) * 64 + c], w3 = lsW[(kc + 3) * 64 + c];
            float w4 = lsW[(kc + 4) * 64 + c], w5 = lsW[(kc + 5) * 64 + c];
            float w6 = lsW[(kc + 6) * 64 + c], w7 = lsW[(kc + 7) * 64 + c];
#pragma unroll
            for (int r = 0; r < 16; ++r) {
                const float4* xp = (const float4*)&lsX[(rbase + r) * K + kc];
                float4 xa = xp[0], xb = xp[1];   // LDS broadcast reads
                acc[r] += xa.x * w0 + xa.y * w1 + xa.z * w2 + xa.w * w3
                        + xb.x * w4 + xb.y * w5 + xb.z * w6 + xb.w * w7;
            }
        }
        long long ob = (long long)row0 * 64;
#pragma unroll
        for (int r = 0; r < 16; ++r) {
            int rr = rbase + r;
            if (rr < nrows) {
                float v = acc[r];
                if (dscale) v *= dscale[row0 + rr];
                if (OUTBF) ((__hip_bfloat16*)Out)[ob + (long long)rr * 64 + c] = __float2bfloat16(v);
                else       ((float*)Out)[ob + (long long)rr * 64 + c] = v;
            }
        }
    }
}

// ---------- CSR gather over bf16 Hs (pre-scaled by dinv); bf16 out with out_scale ----------
__global__ void gather_bf(const __hip_bfloat16* __restrict__ Hs,
                          const int* __restrict__ row_start,
                          const int* __restrict__ csr_src,
                          const float* __restrict__ dinv,
                          const void* bias, const int* __restrict__ flags,
                          const float* __restrict__ out_scale,
                          __hip_bfloat16* __restrict__ Hout, int N) {
    int isf32 = flags[0];
    int c = threadIdx.x & 63;
    int n = blockIdx.x * 4 + (threadIdx.x >> 6);
    if (n >= N) return;
    int beg = row_start[n], end = row_start[n + 1];
    float a0 = __bfloat162float(Hs[(long long)n * 64 + c]);   // self term (already ×dinv[n])
    float a1 = 0.f;
    int i = beg;
    for (; i + 3 < end; i += 4) {
        int s0 = csr_src[i], s1 = csr_src[i + 1], s2 = csr_src[i + 2], s3 = csr_src[i + 3];
        float h0 = __bfloat162float(Hs[(long long)s0 * 64 + c]);
        float h1 = __bfloat162float(Hs[(long long)s1 * 64 + c]);
        float h2 = __bfloat162float(Hs[(long long)s2 * 64 + c]);
        float h3 = __bfloat162float(Hs[(long long)s3 * 64 + c]);
        a0 += h0 + h2;
        a1 += h1 + h3;
    }
    for (; i < end; ++i)
        a0 += __bfloat162float(Hs[(long long)csr_src[i] * 64 + c]);
    float v = (a0 + a1) * dinv[n] + ld_f(bias, c, isf32);
    float r = v > 0.f ? v : 0.f;
    r *= out_scale[n];
    Hout[(long long)n * 64 + c] = __float2bfloat16(r);
}

// ---------- fused gather2 + mean-pool: persistent blocks, LDS partials ----------
__global__ void gather_pool(const __hip_bfloat16* __restrict__ Hs,
                            const int* __restrict__ row_start,
                            const int* __restrict__ csr_src,
                            const float* __restrict__ dinv,
                            const void* bias, const void* batch,
                            const int* __restrict__ flags,
                            float* __restrict__ pooled, float* __restrict__ cnt, int N) {
    __shared__ float part[NG * 64];
    __shared__ float scnt[NG];
    int isf32 = flags[0];
    int b64   = flags[2];
    int tid = threadIdx.x;
    for (int i = tid; i < NG * 64; i += 256) part[i] = 0.f;
    if (tid < NG) scnt[tid] = 0.f;
    __syncthreads();
    int c = tid & 63;
    int sub = tid >> 6;
    float bc = ld_f(bias, c, isf32);
    for (int n = blockIdx.x * 4 + sub; n < N; n += gridDim.x * 4) {
        int beg = row_start[n], end = row_start[n + 1];
        float a0 = __bfloat162float(Hs[(long long)n * 64 + c]);
        float a1 = 0.f;
        int i = beg;
        for (; i + 3 < end; i += 4) {
            int s0 = csr_src[i], s1 = csr_src[i + 1], s2 = csr_src[i + 2], s3 = csr_src[i + 3];
            float h0 = __bfloat162float(Hs[(long long)s0 * 64 + c]);
            float h1 = __bfloat162float(Hs[(long long)s1 * 64 + c]);
            float h2 = __bfloat162float(Hs[(long long)s2 * 64 + c]);
            float h3 = __bfloat162float(Hs[(long long)s3 * 64 + c]);
            a0 += h0 + h2;
            a1 += h1 + h3;
        }
        for (; i < end; ++i)
            a0 += __bfloat162float(Hs[(long long)csr_src[i] * 64 + c]);
        float v = (a0 + a1) * dinv[n] + bc;
        float r = v > 0.f ? v : 0.f;
        int g = ld_idx(batch, n, b64);
        if ((unsigned)g < (unsigned)NG) {
            atomicAdd(&part[g * 64 + c], r);
            if (c == 0) atomicAdd(&scnt[g], 1.0f);
        }
    }
    __syncthreads();
    for (int i = tid; i < NG * 64; i += 256) {
        float v = part[i];
        if (v != 0.f) atomicAdd(&pooled[i], v);
    }
    if (tid < NG && scnt[tid] != 0.f) atomicAdd(&cnt[tid], scnt[tid]);
}

// ---------- final ----------
__global__ void final_kernel(const float* __restrict__ pooled, const float* __restrict__ cnt,
                             const void* lw, const void* lb,
                             const int* __restrict__ flags, void* out) {
    int isf32 = flags[0];
    int g = threadIdx.x;
    if (g >= NG) return;
    float inv = 1.0f / fmaxf(cnt[g], 1.0f);
    float logits[10];
    for (int c = 0; c < 10; ++c) logits[c] = ld_f(lb, c, isf32);
    for (int k = 0; k < 64; ++k) {
        float m = pooled[g * 64 + k] * inv;
        for (int c = 0; c < 10; ++c)
            logits[c] += m * ld_f(lw, k * 10 + c, isf32);
    }
    float mx = logits[0];
    for (int c = 1; c < 10; ++c) mx = fmaxf(mx, logits[c]);
    float se = 0.f;
    for (int c = 0; c < 10; ++c) se += __expf(logits[c] - mx);
    float lse = mx + __logf(se);
    if (isf32) {
        float* o = (float*)out;
        for (int c = 0; c < 10; ++c) o[g * 10 + c] = logits[c] - lse;
    } else {
        __hip_bfloat16* o = (__hip_bfloat16*)out;
        for (int c = 0; c < 10; ++c) o[g * 10 + c] = __float2bfloat16(logits[c] - lse);
    }
}

// ---------- fallback pipeline kernels (round-2 proven, atomic scatter, fp32) ----------
__global__ void count_kernel(const void* ei, const int* __restrict__ flags,
                             int* __restrict__ deg, int E) {
    int is64 = flags[1];
    int i = blockIdx.x * blockDim.x + threadIdx.x;
    int stride = gridDim.x * blockDim.x;
    for (; i < E; i += stride) {
        int d = ld_idx(ei, (long long)E + i, is64);
        if ((unsigned)d < (unsigned)NNODES) atomicAdd(&deg[d], 1);
    }
}

__global__ void dinv_kernel(const int* __restrict__ deg, float* __restrict__ dinv, int N) {
    int i = blockIdx.x * blockDim.x + threadIdx.x;
    if (i < N) dinv[i] = rsqrtf((float)deg[i] + 1.0f);
}

__global__ void scatter_kernel(const float* __restrict__ H, const void* ei,
                               const int* __restrict__ flags,
                               const float* __restrict__ dinv,
                               float* __restrict__ agg, int E) {
    int is64 = flags[1];
    int lane = threadIdx.x & 63;
    int e = blockIdx.x * 4 + (threadIdx.x >> 6);
    if (e >= E) return;
    int s = ld_idx(ei, e, is64);
    int d = ld_idx(ei, (long long)E + e, is64);
    if ((unsigned)s >= (unsigned)NNODES || (unsigned)d >= (unsigned)NNODES) return;
    float nrm = dinv[s] * dinv[d];
    float v = H[(long long)s * 64 + lane] * nrm;
    atomicAdd(&agg[(long long)d * 64 + lane], v);
}

__global__ void relu_bias_kernel(float* __restrict__ H, const float* __restrict__ agg,
                                 const float* __restrict__ dinv, const void* b,
                                 const int* __restrict__ flags, int N) {
    int isf32 = flags[0];
    long long idx = (long long)blockIdx.x * blockDim.x + threadIdx.x;
    if (idx >= (long long)N * 64) return;
    int n = (int)(idx >> 6);
    int c = (int)(idx & 63);
    float dv = dinv[n];
    float v = agg[idx] + H[idx] * dv * dv + ld_f(b, c, isf32);
    H[idx] = v > 0.f ? v : 0.f;
}

__global__ void pool_fb_kernel(const float* __restrict__ agg, const float* __restrict__ Hg,
                               const float* __restrict__ dinv, const void* b,
                               const void* batch, const int* __restrict__ flags,
                               float* __restrict__ pooled, float* __restrict__ cnt, int N) {
    __shared__ float part[NG * 64];
    __shared__ float scnt[NG];
    int isf32 = flags[0];
    int b64   = flags[2];
    int tid = threadIdx.x;
    for (int i = tid; i < NG * 64; i += blockDim.x) part[i] = 0.f;
    if (tid < NG) scnt[tid] = 0.f;
    __syncthreads();
    int c = tid & 63;
    int sub = tid >> 6;
    float bc = ld_f(b, c, isf32);
    for (int n = blockIdx.x * 4 + sub; n < N; n += gridDim.x * 4) {
        int g = ld_idx(batch, n, b64);
        if ((unsigned)g >= (unsigned)NG) continue;
        float dv = dinv[n];
        float v = agg[(long long)n * 64 + c] + Hg[(long long)n * 64 + c] * dv * dv + bc;
        v = v > 0.f ? v : 0.f;
        atomicAdd(&part[g * 64 + c], v);
        if (c == 0) atomicAdd(&scnt[g], 1.0f);
    }
    __syncthreads();
    for (int i = tid; i < NG * 64; i += blockDim.x) {
        float v = part[i];
        if (v != 0.f) atomicAdd(&pooled[i], v);
    }
    if (tid < NG && scnt[tid] != 0.f) atomicAdd(&cnt[tid], scnt[tid]);
}

__global__ void zero_out_kernel(unsigned short* out, int n16) {
    int i = blockIdx.x * blockDim.x + threadIdx.x;
    if (i < n16) out[i] = 0;
}

extern "C" void kernel_launch(void* const* d_in, const int* in_sizes, int n_in,
                              void* d_out, int out_size, void* d_ws, size_t ws_size,
                              hipStream_t stream) {
    const void* x   = d_in[0];
    const void* ei  = d_in[1];   // [2, E] flat: src then dst
    const void* bat = d_in[2];
    const void* W1  = d_in[3];
    const void* b1  = d_in[4];
    const void* W2  = d_in[5];
    const void* b2  = d_in[6];
    const void* lw  = d_in[7];
    const void* lb  = d_in[8];

    const int N = NNODES, E = NEDGES;
    int* ws = (int*)d_ws;
    const int NT = (N + 63) / 64;    // gemm tiles

    // ---- CSR-path layout (words). staging aliases bufA (dead before GEMM1). ----
    const long long o_flags = 0;                          // 16
    const long long o_deg   = 16;                         // N (CSR path: scan sums live here)
    const long long o_dinv  = 16 + (long long)N;          // N
    const long long o_rs    = 16 + 2LL * N;               // N+1
    const long long o_bcnt  = 300032;                     // SCAN_M+1 = 50177
    const long long o_pool  = 350272;                     // NG*64
    const long long o_cnt   = o_pool + NG * 64;           // NG
    const long long o_csr   = 354432;                     // E
    const long long o_bufA  = o_csr + E;                  // N*64 words (bf16 uses half)
    const long long o_bufB  = o_bufA + (long long)N * 64; // N*64 words
    const size_t need_csr = (size_t)(o_bufB + (long long)N * 64) * 4;   // ~65.4 MB

    // ---- fallback layout ----
    const size_t need_fb = (size_t)(204800 + 2LL * N * 64) * 4;

    if (ws_size >= need_csr) {
        int*      flags   = ws + o_flags;
        int*      bsums   = ws + o_deg;       // SCAN_NB+1 words
        float*    dinv    = (float*)(ws + o_dinv);
        int*      rs      = ws + o_rs;
        int*      bcnt    = ws + o_bcnt;
        float*    pooled  = (float*)(ws + o_pool);
        float*    cnt     = (float*)(ws + o_cnt);
        int*      csr     = ws + o_csr;
        unsigned* staging = (unsigned*)(ws + o_bufA);     // alias: dead before GEMM1
        __hip_bfloat16* hA = (__hip_bfloat16*)(ws + o_bufA);
        __hip_bfloat16* hB = (__hip_bfloat16*)(ws + o_bufB);

        detect_kernel<<<1, 256, 0, stream>>>(x, ei, bat, flags);
        hipMemsetAsync(pooled, 0, (NG * 64 + NG) * sizeof(float), stream);

        // binned CSR build: no global atomics, no serial scans, packed 4B staging
        binA_count<<<PB, 256, 0, stream>>>(ei, flags, bcnt, E);
        scanP1<<<SCAN_NB, 1024, 0, stream>>>(bcnt, bsums);
        scanP2<<<1, 64, 0, stream>>>(bsums);
        scanP3<<<SCAN_NB, 1024, 0, stream>>>(bcnt, bsums);
        binA_write<<<PB, 256, 0, stream>>>(ei, flags, bcnt, staging, E);
        binB_deg_rs<<<NBUCK, 256, 0, stream>>>(staging, bcnt, rs, dinv);
        binB_fill<<<NBUCK, 256, 0, stream>>>(staging, bcnt, rs, csr);

        // layer 1: gemm1 -> bf16 dinv*(x@W1); gather1 -> bf16 dinv*relu(...)
        gemm_tile<128, 0, 1><<<NT, 256, 0, stream>>>(x, W1, flags, dinv, hA, N);
        gather_bf<<<(N + 3) / 4, 256, 0, stream>>>(hA, rs, csr, dinv, b1, flags, dinv, hB, N);
        // layer 2: gemm2 bf16 ws -> bf16 out; fused gather2+pool
        gemm_tile<64, 2, 1><<<NT, 256, 0, stream>>>(hB, W2, flags, nullptr, hA, N);
        gather_pool<<<512, 256, 0, stream>>>(hA, rs, csr, dinv, b2, bat, flags, pooled, cnt, N);

        final_kernel<<<1, 64, 0, stream>>>(pooled, cnt, lw, lb, flags, d_out);
    } else if (ws_size >= need_fb) {
        int*   flags  = ws;
        int*   deg    = ws + 16;
        float* dinv   = (float*)(ws + 16 + N);
        float* pooled = (float*)(ws + 16 + 2LL * N);
        float* cnt    = pooled + NG * 64;
        float* bufA   = (float*)(ws + 204800);
        float* bufB   = bufA + (long long)N * 64;

        detect_kernel<<<1, 256, 0, stream>>>(x, ei, bat, flags);
        hipMemsetAsync(deg, 0, N * sizeof(int), stream);
        hipMemsetAsync(pooled, 0, (NG * 64 + NG) * sizeof(float), stream);

        count_kernel<<<2048, 256, 0, stream>>>(ei, flags, deg, E);
        dinv_kernel<<<(N + 255) / 256, 256, 0, stream>>>(deg, dinv, N);

        gemm_tile<128, 0, 0><<<NT, 256, 0, stream>>>(x, W1, flags, nullptr, bufA, N);
        hipMemsetAsync(bufB, 0, (size_t)N * 64 * sizeof(float), stream);
        scatter_kernel<<<(E + 3) / 4, 256, 0, stream>>>(bufA, ei, flags, dinv, bufB, E);
        relu_bias_kernel<<<((long long)N * 64 + 255) / 256, 256, 0, stream>>>(bufA, bufB, dinv, b1, flags, N);

        gemm_tile<64, 1, 0><<<NT, 256, 0, stream>>>(bufA, W2, flags, nullptr, bufB, N);
        hipMemsetAsync(bufA, 0, (size_t)N * 64 * sizeof(float), stream);
        scatter_kernel<<<(E + 3) / 4, 256, 0, stream>>>(bufB, ei, flags, dinv, bufA, E);

        pool_fb_kernel<<<512, 256, 0, stream>>>(bufA, bufB, dinv, b2, bat, flags, pooled, cnt, N);
        final_kernel<<<1, 64, 0, stream>>>(pooled, cnt, lw, lb, flags, d_out);
    } else {
        zero_out_kernel<<<(out_size * 2 + 255) / 256, 256, 0, stream>>>(
            (unsigned short*)d_out, out_size);
    }
}

// Round 10
// 618.216 us; speedup vs baseline: 1.2548x; 1.2548x over previous
//
#include <hip/hip_runtime.h>
#include <hip/hip_bf16.h>

#define NNODES 100000
#define NEDGES 3200000
#define NG     64
#define NBUCK  196          // ceil(NNODES/512) buckets of 512 dst nodes
#define PB     256          // phase-A partition blocks
#define SCAN_M (PB * NBUCK) // 50176
#define SCAN_NB ((SCAN_M + 1023) / 1024)   // 49

// ---------- dtype-flexible loads (flags are wave-uniform) ----------
__device__ __forceinline__ int ld_idx(const void* p, long long i, int is64) {
    if (is64) return (int)((const long long*)p)[i];
    return ((const int*)p)[i];
}
__device__ __forceinline__ float ld_f(const void* p, long long i, int isf32) {
    if (isf32) return ((const float*)p)[i];
    return __bfloat162float(((const __hip_bfloat16*)p)[i]);
}
__device__ __forceinline__ float bfbits(unsigned b) {
    return __uint_as_float(b << 16);
}

// ---------- runtime dtype detection (parallel, 256 threads) ----------
__global__ void detect_kernel(const void* x, const void* ei, const void* bat, int* flags) {
    __shared__ int f[3];
    int t = threadIdx.x;
    if (t < 3) f[t] = 0;
    __syncthreads();
    const unsigned short* u = (const unsigned short*)x;
    int e = (u[t] >> 7) & 0xFF;
    if (e >= 0x90) atomicOr(&f[0], 1);                 // fp32-reinterpret signature
    const unsigned* w = (const unsigned*)ei;
    if (w[2 * t + 1] != 0u) atomicOr(&f[1], 1);        // odd word nonzero -> int32
    const unsigned* bw = (const unsigned*)bat;
    if (bw[50001 + 2 * t] != 0u) atomicOr(&f[2], 1);   // mid-array odd words
    __syncthreads();
    if (t == 0) { flags[0] = f[0]; flags[1] = !f[1]; flags[2] = !f[2]; }
}

// ---------- phase A1: per-(bucket,block) edge counts (LDS only) ----------
__global__ void binA_count(const void* ei, const int* __restrict__ flags,
                           int* __restrict__ bcnt, int E) {
    __shared__ int cnt[NBUCK];
    int is64 = flags[1];
    for (int i = threadIdx.x; i < NBUCK; i += 256) cnt[i] = 0;
    __syncthreads();
    const int chunk = (E + PB - 1) / PB;
    int beg = blockIdx.x * chunk, end = min(E, beg + chunk);
    for (int i = beg + threadIdx.x; i < end; i += 256) {
        int s = ld_idx(ei, i, is64);
        int d = ld_idx(ei, (long long)E + i, is64);
        if ((unsigned)s < (unsigned)NNODES && (unsigned)d < (unsigned)NNODES)
            atomicAdd(&cnt[d >> 9], 1);
    }
    __syncthreads();
    for (int i = threadIdx.x; i < NBUCK; i += 256)
        bcnt[i * PB + blockIdx.x] = cnt[i];     // bucket-major for scan
}

// ---------- parallel 3-phase exclusive scan over bcnt[SCAN_M] ----------
__global__ void scanP1(int* __restrict__ a, int* __restrict__ sums) {
    __shared__ int ls[1024];
    int t = threadIdx.x;
    int i = blockIdx.x * 1024 + t;
    int v = (i < SCAN_M) ? a[i] : 0;
    ls[t] = v;
    __syncthreads();
    for (int off = 1; off < 1024; off <<= 1) {
        int p = (t >= off) ? ls[t - off] : 0;
        __syncthreads();
        ls[t] += p;
        __syncthreads();
    }
    if (i < SCAN_M) a[i] = ls[t] - v;           // exclusive within block
    if (t == 1023) sums[blockIdx.x] = ls[1023]; // block total
}

__global__ void scanP2(int* __restrict__ sums) {
    __shared__ int ls[SCAN_NB];
    int t = threadIdx.x;
    if (t < SCAN_NB) ls[t] = sums[t];
    __syncthreads();
    if (t == 0) {
        int run = 0;
        for (int i = 0; i < SCAN_NB; ++i) { int c = ls[i]; ls[i] = run; run += c; }
        sums[SCAN_NB] = run;                    // grand total
    }
    __syncthreads();
    if (t < SCAN_NB) sums[t] = ls[t];
}

__global__ void scanP3(int* __restrict__ a, const int* __restrict__ sums) {
    int i = blockIdx.x * 1024 + threadIdx.x;
    if (i < SCAN_M) a[i] += sums[blockIdx.x];
    if (i == 0) a[SCAN_M] = sums[SCAN_NB];      // bcnt[M] = total
}

// ---------- phase A3: partition edges into bucket-ordered packed staging ----------
// pack: s (17 bits) | (d - bucket_lo) << 17  (9 bits) -> 4 B per edge
__global__ void binA_write(const void* ei, const int* __restrict__ flags,
                           const int* __restrict__ bcnt, unsigned* __restrict__ staging, int E) {
    __shared__ int cur[NBUCK];
    int is64 = flags[1];
    for (int i = threadIdx.x; i < NBUCK; i += 256) cur[i] = bcnt[i * PB + blockIdx.x];
    __syncthreads();
    const int chunk = (E + PB - 1) / PB;
    int beg = blockIdx.x * chunk, end = min(E, beg + chunk);
    for (int i = beg + threadIdx.x; i < end; i += 256) {
        int s = ld_idx(ei, i, is64);
        int d = ld_idx(ei, (long long)E + i, is64);
        if ((unsigned)s < (unsigned)NNODES && (unsigned)d < (unsigned)NNODES) {
            int pos = atomicAdd(&cur[d >> 9], 1);
            staging[pos] = (unsigned)s | ((unsigned)(d & 511) << 17);
        }
    }
}

// ---------- phase B1 (fused): per-bucket degrees -> rs (local scan + bucket base) + dinv ----------
__global__ void binB_deg_rs(const unsigned* __restrict__ staging, const int* __restrict__ bcnt,
                            int* __restrict__ rs, float* __restrict__ dinv) {
    __shared__ int dcnt[512];
    __shared__ int ls[256];
    int b = blockIdx.x;
    int lo = b << 9;
    int t = threadIdx.x;
    for (int i = t; i < 512; i += 256) dcnt[i] = 0;
    __syncthreads();
    int beg = bcnt[b * PB], end = bcnt[(b + 1) * PB];
    for (int i = beg + t; i < end; i += 256)
        atomicAdd(&dcnt[staging[i] >> 17], 1);
    __syncthreads();
    int a  = dcnt[2 * t];
    int b2 = dcnt[2 * t + 1];
    int csum = a + b2;
    ls[t] = csum;
    __syncthreads();
    for (int off = 1; off < 256; off <<= 1) {
        int p = (t >= off) ? ls[t - off] : 0;
        __syncthreads();
        ls[t] += p;
        __syncthreads();
    }
    int pref = ls[t] - csum;                    // exclusive prefix of this 2-chunk
    int n0 = lo + 2 * t, n1 = lo + 2 * t + 1;
    if (n0 < NNODES) { rs[n0] = beg + pref;     dinv[n0] = rsqrtf((float)a + 1.0f); }
    if (n1 < NNODES) { rs[n1] = beg + pref + a; dinv[n1] = rsqrtf((float)b2 + 1.0f); }
    if (b == NBUCK - 1 && t == 0) rs[NNODES] = bcnt[SCAN_M];
}

// ---------- phase B2: per-bucket CSR fill (LDS cursors; dense write regions) ----------
__global__ void binB_fill(const unsigned* __restrict__ staging, const int* __restrict__ bcnt,
                          const int* __restrict__ rs, int* __restrict__ csr) {
    __shared__ int cur[512];
    int b = blockIdx.x;
    int lo = b << 9;
    for (int i = threadIdx.x; i < 512; i += 256)
        cur[i] = (lo + i < NNODES) ? rs[lo + i] : 0;
    __syncthreads();
    int beg = bcnt[b * PB], end = bcnt[(b + 1) * PB];
    for (int i = beg + threadIdx.x; i < end; i += 256) {
        unsigned u = staging[i];
        int pos = atomicAdd(&cur[u >> 17], 1);
        csr[pos] = (int)(u & 0x1FFFFu);
    }
}

// ---------- GEMM: X-tile (64 rows) + W staged in LDS; spill-proof (round-7 proven) ----------
// XMODE 0: X has detected dtype; 1: fp32 workspace; 2: bf16 workspace.
// OUTBF 0: fp32 out; 1: bf16 out.
template <int K, int XMODE, int OUTBF>
__global__ __launch_bounds__(256)
void gemm_tile(const void* __restrict__ X, const void* __restrict__ W,
               const int* __restrict__ flags, const float* __restrict__ dscale,
               void* __restrict__ Out, int N) {
    __shared__ float lsW[K * 64];     // [k][c]
    __shared__ float lsX[64 * K];     // [r][k], fp32 after conversion
    int isf32 = flags[0];
    for (int i = threadIdx.x; i < K * 64; i += 256) lsW[i] = ld_f(W, i, isf32);

    int c  = threadIdx.x & 63;
    int wv = threadIdx.x >> 6;        // wave owns rows [wv*16, wv*16+16)
    int ntiles = (N + 63) >> 6;

    for (int t = blockIdx.x; t < ntiles; t += gridDim.x) {
        int row0 = t << 6;
        int nrows = min(64, N - row0);
        int total = nrows * K;
        __syncthreads();              // prev-tile readers done (also covers lsW on 1st iter)
        if (XMODE == 1 || (XMODE == 0 && isf32)) {
            const float* Xb = (const float*)X + (long long)row0 * K;
            for (int i = threadIdx.x; i < total; i += 256) lsX[i] = Xb[i];
        } else {
            const unsigned short* Xb = (const unsigned short*)X + (long long)row0 * K;
            for (int i = threadIdx.x; i < total; i += 256) lsX[i] = bfbits((unsigned)Xb[i]);
        }
        __syncthreads();

        int rbase = wv * 16;
        float acc[16];
#pragma unroll
        for (int r = 0; r < 16; ++r) acc[r] = 0.f;
#pragma unroll 1
        for (int kc = 0; kc < K; kc += 8) {
            float w0 = lsW[(kc + 0) * 64 + c], w1 = lsW[(kc + 1) * 64 + c];
            float w2 = lsW[(kc + 2) * 64 + c], w3 = lsW[(kc + 3) * 64 + c];
            float w4 = lsW[(kc + 4) * 64 + c], w5 = lsW[(kc + 5) * 64 + c];
            float w6 = lsW[(kc + 6) * 64 + c], w7 = lsW[(kc + 7) * 64 + c];
#pragma unroll
            for (int r = 0; r < 16; ++r) {
                const float4* xp = (const float4*)&lsX[(rbase + r) * K + kc];
                float4 xa = xp[0], xb = xp[1];   // LDS broadcast reads
                acc[r] += xa.x * w0 + xa.y * w1 + xa.z * w2 + xa.w * w3
                        + xb.x * w4 + xb.y * w5 + xb.z * w6 + xb.w * w7;
            }
        }
        long long ob = (long long)row0 * 64;
#pragma unroll
        for (int r = 0; r < 16; ++r) {
            int rr = rbase + r;
            if (rr < nrows) {
                float v = acc[r];
                if (dscale) v *= dscale[row0 + rr];
                if (OUTBF) ((__hip_bfloat16*)Out)[ob + (long long)rr * 64 + c] = __float2bfloat16(v);
                else       ((float*)Out)[ob + (long long)rr * 64 + c] = v;
            }
        }
    }
}

// ---------- CSR gather over bf16 Hs (pre-scaled by dinv); bf16 out; optional out_scale ----------
__global__ void gather_bf(const __hip_bfloat16* __restrict__ Hs,
                          const int* __restrict__ row_start,
                          const int* __restrict__ csr_src,
                          const float* __restrict__ dinv,
                          const void* bias, const int* __restrict__ flags,
                          const float* __restrict__ out_scale,
                          __hip_bfloat16* __restrict__ Hout, int N) {
    int isf32 = flags[0];
    int c = threadIdx.x & 63;
    int n = blockIdx.x * 4 + (threadIdx.x >> 6);
    if (n >= N) return;
    int beg = row_start[n], end = row_start[n + 1];
    float a0 = __bfloat162float(Hs[(long long)n * 64 + c]);   // self term (already ×dinv[n])
    float a1 = 0.f;
    int i = beg;
    for (; i + 3 < end; i += 4) {
        int s0 = csr_src[i], s1 = csr_src[i + 1], s2 = csr_src[i + 2], s3 = csr_src[i + 3];
        float h0 = __bfloat162float(Hs[(long long)s0 * 64 + c]);
        float h1 = __bfloat162float(Hs[(long long)s1 * 64 + c]);
        float h2 = __bfloat162float(Hs[(long long)s2 * 64 + c]);
        float h3 = __bfloat162float(Hs[(long long)s3 * 64 + c]);
        a0 += h0 + h2;
        a1 += h1 + h3;
    }
    for (; i < end; ++i)
        a0 += __bfloat162float(Hs[(long long)csr_src[i] * 64 + c]);
    float v = (a0 + a1) * dinv[n] + ld_f(bias, c, isf32);
    float r = v > 0.f ? v : 0.f;
    if (out_scale) r *= out_scale[n];
    Hout[(long long)n * 64 + c] = __float2bfloat16(r);
}

// ---------- pooling over bf16 H ----------
__global__ void pool2_bf(const __hip_bfloat16* __restrict__ H, const void* batch,
                         const int* __restrict__ flags,
                         float* __restrict__ pooled, float* __restrict__ cnt, int N) {
    __shared__ float part[NG * 64];
    __shared__ float scnt[NG];
    int b64 = flags[2];
    int tid = threadIdx.x;
    for (int i = tid; i < NG * 64; i += 256) part[i] = 0.f;
    if (tid < NG) scnt[tid] = 0.f;
    __syncthreads();
    int c = tid & 63;
    int sub = tid >> 6;
    for (int n = blockIdx.x * 4 + sub; n < N; n += gridDim.x * 4) {
        int g = ld_idx(batch, n, b64);
        if ((unsigned)g >= (unsigned)NG) continue;
        atomicAdd(&part[g * 64 + c], __bfloat162float(H[(long long)n * 64 + c]));
        if (c == 0) atomicAdd(&scnt[g], 1.0f);
    }
    __syncthreads();
    for (int i = tid; i < NG * 64; i += 256) {
        float v = part[i];
        if (v != 0.f) atomicAdd(&pooled[i], v);
    }
    if (tid < NG && scnt[tid] != 0.f) atomicAdd(&cnt[tid], scnt[tid]);
}

// ---------- final ----------
__global__ void final_kernel(const float* __restrict__ pooled, const float* __restrict__ cnt,
                             const void* lw, const void* lb,
                             const int* __restrict__ flags, void* out) {
    int isf32 = flags[0];
    int g = threadIdx.x;
    if (g >= NG) return;
    float inv = 1.0f / fmaxf(cnt[g], 1.0f);
    float logits[10];
    for (int c = 0; c < 10; ++c) logits[c] = ld_f(lb, c, isf32);
    for (int k = 0; k < 64; ++k) {
        float m = pooled[g * 64 + k] * inv;
        for (int c = 0; c < 10; ++c)
            logits[c] += m * ld_f(lw, k * 10 + c, isf32);
    }
    float mx = logits[0];
    for (int c = 1; c < 10; ++c) mx = fmaxf(mx, logits[c]);
    float se = 0.f;
    for (int c = 0; c < 10; ++c) se += __expf(logits[c] - mx);
    float lse = mx + __logf(se);
    if (isf32) {
        float* o = (float*)out;
        for (int c = 0; c < 10; ++c) o[g * 10 + c] = logits[c] - lse;
    } else {
        __hip_bfloat16* o = (__hip_bfloat16*)out;
        for (int c = 0; c < 10; ++c) o[g * 10 + c] = __float2bfloat16(logits[c] - lse);
    }
}

// ---------- fallback pipeline kernels (round-2 proven, atomic scatter, fp32) ----------
__global__ void count_kernel(const void* ei, const int* __restrict__ flags,
                             int* __restrict__ deg, int E) {
    int is64 = flags[1];
    int i = blockIdx.x * blockDim.x + threadIdx.x;
    int stride = gridDim.x * blockDim.x;
    for (; i < E; i += stride) {
        int d = ld_idx(ei, (long long)E + i, is64);
        if ((unsigned)d < (unsigned)NNODES) atomicAdd(&deg[d], 1);
    }
}

__global__ void dinv_kernel(const int* __restrict__ deg, float* __restrict__ dinv, int N) {
    int i = blockIdx.x * blockDim.x + threadIdx.x;
    if (i < N) dinv[i] = rsqrtf((float)deg[i] + 1.0f);
}

__global__ void scatter_kernel(const float* __restrict__ H, const void* ei,
                               const int* __restrict__ flags,
                               const float* __restrict__ dinv,
                               float* __restrict__ agg, int E) {
    int is64 = flags[1];
    int lane = threadIdx.x & 63;
    int e = blockIdx.x * 4 + (threadIdx.x >> 6);
    if (e >= E) return;
    int s = ld_idx(ei, e, is64);
    int d = ld_idx(ei, (long long)E + e, is64);
    if ((unsigned)s >= (unsigned)NNODES || (unsigned)d >= (unsigned)NNODES) return;
    float nrm = dinv[s] * dinv[d];
    float v = H[(long long)s * 64 + lane] * nrm;
    atomicAdd(&agg[(long long)d * 64 + lane], v);
}

__global__ void relu_bias_kernel(float* __restrict__ H, const float* __restrict__ agg,
                                 const float* __restrict__ dinv, const void* b,
                                 const int* __restrict__ flags, int N) {
    int isf32 = flags[0];
    long long idx = (long long)blockIdx.x * blockDim.x + threadIdx.x;
    if (idx >= (long long)N * 64) return;
    int n = (int)(idx >> 6);
    int c = (int)(idx & 63);
    float dv = dinv[n];
    float v = agg[idx] + H[idx] * dv * dv + ld_f(b, c, isf32);
    H[idx] = v > 0.f ? v : 0.f;
}

__global__ void pool_fb_kernel(const float* __restrict__ agg, const float* __restrict__ Hg,
                               const float* __restrict__ dinv, const void* b,
                               const void* batch, const int* __restrict__ flags,
                               float* __restrict__ pooled, float* __restrict__ cnt, int N) {
    __shared__ float part[NG * 64];
    __shared__ float scnt[NG];
    int isf32 = flags[0];
    int b64   = flags[2];
    int tid = threadIdx.x;
    for (int i = tid; i < NG * 64; i += blockDim.x) part[i] = 0.f;
    if (tid < NG) scnt[tid] = 0.f;
    __syncthreads();
    int c = tid & 63;
    int sub = tid >> 6;
    float bc = ld_f(b, c, isf32);
    for (int n = blockIdx.x * 4 + sub; n < N; n += gridDim.x * 4) {
        int g = ld_idx(batch, n, b64);
        if ((unsigned)g >= (unsigned)NG) continue;
        float dv = dinv[n];
        float v = agg[(long long)n * 64 + c] + Hg[(long long)n * 64 + c] * dv * dv + bc;
        v = v > 0.f ? v : 0.f;
        atomicAdd(&part[g * 64 + c], v);
        if (c == 0) atomicAdd(&scnt[g], 1.0f);
    }
    __syncthreads();
    for (int i = tid; i < NG * 64; i += blockDim.x) {
        float v = part[i];
        if (v != 0.f) atomicAdd(&pooled[i], v);
    }
    if (tid < NG && scnt[tid] != 0.f) atomicAdd(&cnt[tid], scnt[tid]);
}

__global__ void zero_out_kernel(unsigned short* out, int n16) {
    int i = blockIdx.x * blockDim.x + threadIdx.x;
    if (i < n16) out[i] = 0;
}

extern "C" void kernel_launch(void* const* d_in, const int* in_sizes, int n_in,
                              void* d_out, int out_size, void* d_ws, size_t ws_size,
                              hipStream_t stream) {
    const void* x   = d_in[0];
    const void* ei  = d_in[1];   // [2, E] flat: src then dst
    const void* bat = d_in[2];
    const void* W1  = d_in[3];
    const void* b1  = d_in[4];
    const void* W2  = d_in[5];
    const void* b2  = d_in[6];
    const void* lw  = d_in[7];
    const void* lb  = d_in[8];

    const int N = NNODES, E = NEDGES;
    int* ws = (int*)d_ws;
    const int NT = (N + 63) / 64;    // gemm tiles

    // ---- CSR-path layout (words). staging aliases bufA (dead before GEMM1). ----
    const long long o_flags = 0;                          // 16
    const long long o_deg   = 16;                         // N (CSR path: scan sums live here)
    const long long o_dinv  = 16 + (long long)N;          // N
    const long long o_rs    = 16 + 2LL * N;               // N+1
    const long long o_bcnt  = 300032;                     // SCAN_M+1 = 50177
    const long long o_pool  = 350272;                     // NG*64
    const long long o_cnt   = o_pool + NG * 64;           // NG
    const long long o_csr   = 354432;                     // E
    const long long o_bufA  = o_csr + E;                  // N*64 words (bf16 uses half)
    const long long o_bufB  = o_bufA + (long long)N * 64; // N*64 words
    const size_t need_csr = (size_t)(o_bufB + (long long)N * 64) * 4;   // ~65.4 MB

    // ---- fallback layout ----
    const size_t need_fb = (size_t)(204800 + 2LL * N * 64) * 4;

    if (ws_size >= need_csr) {
        int*      flags   = ws + o_flags;
        int*      bsums   = ws + o_deg;       // SCAN_NB+1 words
        float*    dinv    = (float*)(ws + o_dinv);
        int*      rs      = ws + o_rs;
        int*      bcnt    = ws + o_bcnt;
        float*    pooled  = (float*)(ws + o_pool);
        float*    cnt     = (float*)(ws + o_cnt);
        int*      csr     = ws + o_csr;
        unsigned* staging = (unsigned*)(ws + o_bufA);     // alias: dead before GEMM1
        __hip_bfloat16* hA = (__hip_bfloat16*)(ws + o_bufA);
        __hip_bfloat16* hB = (__hip_bfloat16*)(ws + o_bufB);

        detect_kernel<<<1, 256, 0, stream>>>(x, ei, bat, flags);
        hipMemsetAsync(pooled, 0, (NG * 64 + NG) * sizeof(float), stream);

        // binned CSR build: no global atomics, no serial scans, packed 4B staging
        binA_count<<<PB, 256, 0, stream>>>(ei, flags, bcnt, E);
        scanP1<<<SCAN_NB, 1024, 0, stream>>>(bcnt, bsums);
        scanP2<<<1, 64, 0, stream>>>(bsums);
        scanP3<<<SCAN_NB, 1024, 0, stream>>>(bcnt, bsums);
        binA_write<<<PB, 256, 0, stream>>>(ei, flags, bcnt, staging, E);
        binB_deg_rs<<<NBUCK, 256, 0, stream>>>(staging, bcnt, rs, dinv);
        binB_fill<<<NBUCK, 256, 0, stream>>>(staging, bcnt, rs, csr);

        // layer 1: gemm1 -> bf16 dinv*(x@W1); gather1 -> bf16 dinv*relu(...)
        gemm_tile<128, 0, 1><<<NT, 256, 0, stream>>>(x, W1, flags, dinv, hA, N);
        gather_bf<<<(N + 3) / 4, 256, 0, stream>>>(hA, rs, csr, dinv, b1, flags, dinv, hB, N);
        // layer 2: gemm2 bf16 -> bf16; standalone gather (full occupancy) -> bf16 H
        gemm_tile<64, 2, 1><<<NT, 256, 0, stream>>>(hB, W2, flags, nullptr, hA, N);
        gather_bf<<<(N + 3) / 4, 256, 0, stream>>>(hA, rs, csr, dinv, b2, flags, nullptr, hB, N);

        pool2_bf<<<512, 256, 0, stream>>>(hB, bat, flags, pooled, cnt, N);
        final_kernel<<<1, 64, 0, stream>>>(pooled, cnt, lw, lb, flags, d_out);
    } else if (ws_size >= need_fb) {
        int*   flags  = ws;
        int*   deg    = ws + 16;
        float* dinv   = (float*)(ws + 16 + N);
        float* pooled = (float*)(ws + 16 + 2LL * N);
        float* cnt    = pooled + NG * 64;
        float* bufA   = (float*)(ws + 204800);
        float* bufB   = bufA + (long long)N * 64;

        detect_kernel<<<1, 256, 0, stream>>>(x, ei, bat, flags);
        hipMemsetAsync(deg, 0, N * sizeof(int), stream);
        hipMemsetAsync(pooled, 0, (NG * 64 + NG) * sizeof(float), stream);

        count_kernel<<<2048, 256, 0, stream>>>(ei, flags, deg, E);
        dinv_kernel<<<(N + 255) / 256, 256, 0, stream>>>(deg, dinv, N);

        gemm_tile<128, 0, 0><<<NT, 256, 0, stream>>>(x, W1, flags, nullptr, bufA, N);
        hipMemsetAsync(bufB, 0, (size_t)N * 64 * sizeof(float), stream);
        scatter_kernel<<<(E + 3) / 4, 256, 0, stream>>>(bufA, ei, flags, dinv, bufB, E);
        relu_bias_kernel<<<((long long)N * 64 + 255) / 256, 256, 0, stream>>>(bufA, bufB, dinv, b1, flags, N);

        gemm_tile<64, 1, 0><<<NT, 256, 0, stream>>>(bufA, W2, flags, nullptr, bufB, N);
        hipMemsetAsync(bufA, 0, (size_t)N * 64 * sizeof(float), stream);
        scatter_kernel<<<(E + 3) / 4, 256, 0, stream>>>(bufB, ei, flags, dinv, bufA, E);

        pool_fb_kernel<<<512, 256, 0, stream>>>(bufA, bufB, dinv, b2, bat, flags, pooled, cnt, N);
        final_kernel<<<1, 64, 0, stream>>>(pooled, cnt, lw, lb, flags, d_out);
    } else {
        zero_out_kernel<<<(out_size * 2 + 255) / 256, 256, 0, stream>>>(
            (unsigned short*)d_out, out_size);
    }
}

// Round 11
// 560.630 us; speedup vs baseline: 1.3837x; 1.1027x over previous
//
#include <hip/hip_runtime.h>
#include <hip/hip_bf16.h>

#define NNODES 100000
#define NEDGES 3200000
#define NG     64
#define NBUCK  196          // ceil(NNODES/512) buckets of 512 dst nodes
#define PB     256          // phase-A partition blocks
#define SCAN_M (PB * NBUCK) // 50176
#define SCAN_NB ((SCAN_M + 1023) / 1024)   // 49

// ---------- dtype-flexible loads (flags are wave-uniform) ----------
__device__ __forceinline__ int ld_idx(const void* p, long long i, int is64) {
    if (is64) return (int)((const long long*)p)[i];
    return ((const int*)p)[i];
}
__device__ __forceinline__ float ld_f(const void* p, long long i, int isf32) {
    if (isf32) return ((const float*)p)[i];
    return __bfloat162float(((const __hip_bfloat16*)p)[i]);
}
__device__ __forceinline__ float bfbits(unsigned b) {
    return __uint_as_float(b << 16);
}
__device__ __forceinline__ unsigned short bf16b(float v) {
    __hip_bfloat16 h = __float2bfloat16(v);
    return *(unsigned short*)&h;
}

// ---------- runtime dtype detection (parallel, 256 threads) ----------
__global__ void detect_kernel(const void* x, const void* ei, const void* bat, int* flags) {
    __shared__ int f[3];
    int t = threadIdx.x;
    if (t < 3) f[t] = 0;
    __syncthreads();
    const unsigned short* u = (const unsigned short*)x;
    int e = (u[t] >> 7) & 0xFF;
    if (e >= 0x90) atomicOr(&f[0], 1);                 // fp32-reinterpret signature
    const unsigned* w = (const unsigned*)ei;
    if (w[2 * t + 1] != 0u) atomicOr(&f[1], 1);        // odd word nonzero -> int32
    const unsigned* bw = (const unsigned*)bat;
    if (bw[50001 + 2 * t] != 0u) atomicOr(&f[2], 1);   // mid-array odd words
    __syncthreads();
    if (t == 0) { flags[0] = f[0]; flags[1] = !f[1]; flags[2] = !f[2]; }
}

// ---------- phase A1: per-(bucket,block) edge counts (LDS only) ----------
__global__ void binA_count(const void* ei, const int* __restrict__ flags,
                           int* __restrict__ bcnt, int E) {
    __shared__ int cnt[NBUCK];
    int is64 = flags[1];
    for (int i = threadIdx.x; i < NBUCK; i += 256) cnt[i] = 0;
    __syncthreads();
    const int chunk = (E + PB - 1) / PB;
    int beg = blockIdx.x * chunk, end = min(E, beg + chunk);
    for (int i = beg + threadIdx.x; i < end; i += 256) {
        int s = ld_idx(ei, i, is64);
        int d = ld_idx(ei, (long long)E + i, is64);
        if ((unsigned)s < (unsigned)NNODES && (unsigned)d < (unsigned)NNODES)
            atomicAdd(&cnt[d >> 9], 1);
    }
    __syncthreads();
    for (int i = threadIdx.x; i < NBUCK; i += 256)
        bcnt[i * PB + blockIdx.x] = cnt[i];     // bucket-major for scan
}

// ---------- parallel 3-phase exclusive scan over bcnt[SCAN_M] ----------
__global__ void scanP1(int* __restrict__ a, int* __restrict__ sums) {
    __shared__ int ls[1024];
    int t = threadIdx.x;
    int i = blockIdx.x * 1024 + t;
    int v = (i < SCAN_M) ? a[i] : 0;
    ls[t] = v;
    __syncthreads();
    for (int off = 1; off < 1024; off <<= 1) {
        int p = (t >= off) ? ls[t - off] : 0;
        __syncthreads();
        ls[t] += p;
        __syncthreads();
    }
    if (i < SCAN_M) a[i] = ls[t] - v;           // exclusive within block
    if (t == 1023) sums[blockIdx.x] = ls[1023]; // block total
}

__global__ void scanP2(int* __restrict__ sums) {
    __shared__ int ls[SCAN_NB];
    int t = threadIdx.x;
    if (t < SCAN_NB) ls[t] = sums[t];
    __syncthreads();
    if (t == 0) {
        int run = 0;
        for (int i = 0; i < SCAN_NB; ++i) { int c = ls[i]; ls[i] = run; run += c; }
        sums[SCAN_NB] = run;                    // grand total
    }
    __syncthreads();
    if (t < SCAN_NB) sums[t] = ls[t];
}

__global__ void scanP3(int* __restrict__ a, const int* __restrict__ sums) {
    int i = blockIdx.x * 1024 + threadIdx.x;
    if (i < SCAN_M) a[i] += sums[blockIdx.x];
    if (i == 0) a[SCAN_M] = sums[SCAN_NB];      // bcnt[M] = total
}

// ---------- phase A3: partition edges into bucket-ordered packed staging ----------
// pack: s (17 bits) | (d - bucket_lo) << 17  (9 bits) -> 4 B per edge
__global__ void binA_write(const void* ei, const int* __restrict__ flags,
                           const int* __restrict__ bcnt, unsigned* __restrict__ staging, int E) {
    __shared__ int cur[NBUCK];
    int is64 = flags[1];
    for (int i = threadIdx.x; i < NBUCK; i += 256) cur[i] = bcnt[i * PB + blockIdx.x];
    __syncthreads();
    const int chunk = (E + PB - 1) / PB;
    int beg = blockIdx.x * chunk, end = min(E, beg + chunk);
    for (int i = beg + threadIdx.x; i < end; i += 256) {
        int s = ld_idx(ei, i, is64);
        int d = ld_idx(ei, (long long)E + i, is64);
        if ((unsigned)s < (unsigned)NNODES && (unsigned)d < (unsigned)NNODES) {
            int pos = atomicAdd(&cur[d >> 9], 1);
            staging[pos] = (unsigned)s | ((unsigned)(d & 511) << 17);
        }
    }
}

// ---------- phase B (fused): per-bucket degrees -> rs + dinv + CSR fill in one kernel ----------
__global__ void binB_all(const unsigned* __restrict__ staging, const int* __restrict__ bcnt,
                         int* __restrict__ rs, float* __restrict__ dinv,
                         int* __restrict__ csr) {
    __shared__ int dcnt[512];
    __shared__ int ls[256];
    int b = blockIdx.x;
    int lo = b << 9;
    int t = threadIdx.x;
    for (int i = t; i < 512; i += 256) dcnt[i] = 0;
    __syncthreads();
    int beg = bcnt[b * PB], end = bcnt[(b + 1) * PB];
    for (int i = beg + t; i < end; i += 256)
        atomicAdd(&dcnt[staging[i] >> 17], 1);
    __syncthreads();
    int a  = dcnt[2 * t];
    int b2 = dcnt[2 * t + 1];
    int csum = a + b2;
    ls[t] = csum;
    __syncthreads();
    for (int off = 1; off < 256; off <<= 1) {
        int p = (t >= off) ? ls[t - off] : 0;
        __syncthreads();
        ls[t] += p;
        __syncthreads();
    }
    int pref = ls[t] - csum;                    // exclusive prefix of this 2-chunk
    int n0 = lo + 2 * t, n1 = lo + 2 * t + 1;
    if (n0 < NNODES) { rs[n0] = beg + pref;     dinv[n0] = rsqrtf((float)a + 1.0f); }
    if (n1 < NNODES) { rs[n1] = beg + pref + a; dinv[n1] = rsqrtf((float)b2 + 1.0f); }
    if (b == NBUCK - 1 && t == 0) rs[NNODES] = bcnt[SCAN_M];
    __syncthreads();
    dcnt[2 * t]     = beg + pref;               // cursors
    dcnt[2 * t + 1] = beg + pref + a;
    __syncthreads();
    for (int i = beg + t; i < end; i += 256) {  // staging chunk is L2-hot from pass 1
        unsigned u = staging[i];
        int pos = atomicAdd(&dcnt[u >> 17], 1);
        csr[pos] = (int)(u & 0x1FFFFu);
    }
}

// ---------- GEMM: X-tile (64 rows) + W staged in LDS; spill-proof (round-7 proven) ----------
// XMODE 0: X has detected dtype; 1: fp32 workspace; 2: bf16 workspace.
// OUTBF 0: fp32 out; 1: bf16 out.
template <int K, int XMODE, int OUTBF>
__global__ __launch_bounds__(256)
void gemm_tile(const void* __restrict__ X, const void* __restrict__ W,
               const int* __restrict__ flags, const float* __restrict__ dscale,
               void* __restrict__ Out, int N) {
    __shared__ float lsW[K * 64];     // [k][c]
    __shared__ float lsX[64 * K];     // [r][k], fp32 after conversion
    int isf32 = flags[0];
    for (int i = threadIdx.x; i < K * 64; i += 256) lsW[i] = ld_f(W, i, isf32);

    int c  = threadIdx.x & 63;
    int wv = threadIdx.x >> 6;        // wave owns rows [wv*16, wv*16+16)
    int ntiles = (N + 63) >> 6;

    for (int t = blockIdx.x; t < ntiles; t += gridDim.x) {
        int row0 = t << 6;
        int nrows = min(64, N - row0);
        int total = nrows * K;
        __syncthreads();              // prev-tile readers done (also covers lsW on 1st iter)
        if (XMODE == 1 || (XMODE == 0 && isf32)) {
            const float* Xb = (const float*)X + (long long)row0 * K;
            for (int i = threadIdx.x; i < total; i += 256) lsX[i] = Xb[i];
        } else {
            const unsigned short* Xb = (const unsigned short*)X + (long long)row0 * K;
            for (int i = threadIdx.x; i < total; i += 256) lsX[i] = bfbits((unsigned)Xb[i]);
        }
        __syncthreads();

        int rbase = wv * 16;
        float acc[16];
#pragma unroll
        for (int r = 0; r < 16; ++r) acc[r] = 0.f;
#pragma unroll 1
        for (int kc = 0; kc < K; kc += 8) {
            float w0 = lsW[(kc + 0) * 64 + c], w1 = lsW[(kc + 1) * 64 + c];
            float w2 = lsW[(kc + 2) * 64 + c], w3 = lsW[(kc + 3) * 64 + c];
            float w4 = lsW[(kc + 4) * 64 + c], w5 = lsW[(kc + 5) * 64 + c];
            float w6 = lsW[(kc + 6) * 64 + c], w7 = lsW[(kc + 7) * 64 + c];
#pragma unroll
            for (int r = 0; r < 16; ++r) {
                const float4* xp = (const float4*)&lsX[(rbase + r) * K + kc];
                float4 xa = xp[0], xb = xp[1];   // LDS broadcast reads
                acc[r] += xa.x * w0 + xa.y * w1 + xa.z * w2 + xa.w * w3
                        + xb.x * w4 + xb.y * w5 + xb.z * w6 + xb.w * w7;
            }
        }
        long long ob = (long long)row0 * 64;
#pragma unroll
        for (int r = 0; r < 16; ++r) {
            int rr = rbase + r;
            if (rr < nrows) {
                float v = acc[r];
                if (dscale) v *= dscale[row0 + rr];
                if (OUTBF) ((__hip_bfloat16*)Out)[ob + (long long)rr * 64 + c] = __float2bfloat16(v);
                else       ((float*)Out)[ob + (long long)rr * 64 + c] = v;
            }
        }
    }
}

// ---------- vectorized CSR gather: wave = 1 node; lane=(edge e=l>>3, feat-octet f=l&7).
// Each lane loads uint4 (8 bf16) -> 8 edges per wave iteration, 16 B/lane.
// Butterfly-reduce edge groups, lanes e==0 write packed uint4 row. ----------
__global__ __launch_bounds__(256)
void gather_v(const __hip_bfloat16* __restrict__ Hs,
              const int* __restrict__ row_start,
              const int* __restrict__ csr_src,
              const float* __restrict__ dinv,
              const void* bias, const int* __restrict__ flags,
              const float* __restrict__ out_scale,
              __hip_bfloat16* __restrict__ Hout, int N) {
    int isf32 = flags[0];
    int lane = threadIdx.x & 63;
    int e = lane >> 3;          // 0..7 edge slot
    int f = lane & 7;           // 0..7 feature octet (feats 8f..8f+7)
    int n = blockIdx.x * 4 + (threadIdx.x >> 6);
    if (n >= N) return;
    int beg = row_start[n], end = row_start[n + 1];

    float acc[8];
#pragma unroll
    for (int j = 0; j < 8; ++j) acc[j] = 0.f;

    for (int i = beg; i < end; i += 8) {
        int idx = i + e;
        if (idx < end) {
            int s = csr_src[idx];                       // 8-lane broadcast
            const uint4* hp = (const uint4*)(Hs + ((long long)s << 6)) + f;
            uint4 u = *hp;
            acc[0] += bfbits(u.x & 0xffffu); acc[1] += bfbits(u.x >> 16);
            acc[2] += bfbits(u.y & 0xffffu); acc[3] += bfbits(u.y >> 16);
            acc[4] += bfbits(u.z & 0xffffu); acc[5] += bfbits(u.z >> 16);
            acc[6] += bfbits(u.w & 0xffffu); acc[7] += bfbits(u.w >> 16);
        }
    }
#pragma unroll
    for (int j = 0; j < 8; ++j) {
        acc[j] += __shfl_xor(acc[j], 8);
        acc[j] += __shfl_xor(acc[j], 16);
        acc[j] += __shfl_xor(acc[j], 32);
    }
    // self term (pre-scaled by dinv[n]) + bias + relu + optional out_scale
    const uint4* sp = (const uint4*)(Hs + ((long long)n << 6)) + f;
    uint4 su = *sp;
    float self[8] = { bfbits(su.x & 0xffffu), bfbits(su.x >> 16),
                      bfbits(su.y & 0xffffu), bfbits(su.y >> 16),
                      bfbits(su.z & 0xffffu), bfbits(su.z >> 16),
                      bfbits(su.w & 0xffffu), bfbits(su.w >> 16) };
    float dn = dinv[n];
    float osc = out_scale ? out_scale[n] : 1.f;
    if (e == 0) {
        unsigned short h[8];
#pragma unroll
        for (int j = 0; j < 8; ++j) {
            float v = (acc[j] + self[j]) * dn + ld_f(bias, 8 * f + j, isf32);
            float r = v > 0.f ? v : 0.f;
            h[j] = bf16b(r * osc);
        }
        uint4 o;
        o.x = (unsigned)h[0] | ((unsigned)h[1] << 16);
        o.y = (unsigned)h[2] | ((unsigned)h[3] << 16);
        o.z = (unsigned)h[4] | ((unsigned)h[5] << 16);
        o.w = (unsigned)h[6] | ((unsigned)h[7] << 16);
        *((uint4*)(Hout + ((long long)n << 6)) + f) = o;
    }
}

// ---------- pooling over bf16 H ----------
__global__ void pool2_bf(const __hip_bfloat16* __restrict__ H, const void* batch,
                         const int* __restrict__ flags,
                         float* __restrict__ pooled, float* __restrict__ cnt, int N) {
    __shared__ float part[NG * 64];
    __shared__ float scnt[NG];
    int b64 = flags[2];
    int tid = threadIdx.x;
    for (int i = tid; i < NG * 64; i += 256) part[i] = 0.f;
    if (tid < NG) scnt[tid] = 0.f;
    __syncthreads();
    int c = tid & 63;
    int sub = tid >> 6;
    for (int n = blockIdx.x * 4 + sub; n < N; n += gridDim.x * 4) {
        int g = ld_idx(batch, n, b64);
        if ((unsigned)g >= (unsigned)NG) continue;
        atomicAdd(&part[g * 64 + c], __bfloat162float(H[(long long)n * 64 + c]));
        if (c == 0) atomicAdd(&scnt[g], 1.0f);
    }
    __syncthreads();
    for (int i = tid; i < NG * 64; i += 256) {
        float v = part[i];
        if (v != 0.f) atomicAdd(&pooled[i], v);
    }
    if (tid < NG && scnt[tid] != 0.f) atomicAdd(&cnt[tid], scnt[tid]);
}

// ---------- final ----------
__global__ void final_kernel(const float* __restrict__ pooled, const float* __restrict__ cnt,
                             const void* lw, const void* lb,
                             const int* __restrict__ flags, void* out) {
    int isf32 = flags[0];
    int g = threadIdx.x;
    if (g >= NG) return;
    float inv = 1.0f / fmaxf(cnt[g], 1.0f);
    float logits[10];
    for (int c = 0; c < 10; ++c) logits[c] = ld_f(lb, c, isf32);
    for (int k = 0; k < 64; ++k) {
        float m = pooled[g * 64 + k] * inv;
        for (int c = 0; c < 10; ++c)
            logits[c] += m * ld_f(lw, k * 10 + c, isf32);
    }
    float mx = logits[0];
    for (int c = 1; c < 10; ++c) mx = fmaxf(mx, logits[c]);
    float se = 0.f;
    for (int c = 0; c < 10; ++c) se += __expf(logits[c] - mx);
    float lse = mx + __logf(se);
    if (isf32) {
        float* o = (float*)out;
        for (int c = 0; c < 10; ++c) o[g * 10 + c] = logits[c] - lse;
    } else {
        __hip_bfloat16* o = (__hip_bfloat16*)out;
        for (int c = 0; c < 10; ++c) o[g * 10 + c] = __float2bfloat16(logits[c] - lse);
    }
}

// ---------- fallback pipeline kernels (round-2 proven, atomic scatter, fp32) ----------
__global__ void count_kernel(const void* ei, const int* __restrict__ flags,
                             int* __restrict__ deg, int E) {
    int is64 = flags[1];
    int i = blockIdx.x * blockDim.x + threadIdx.x;
    int stride = gridDim.x * blockDim.x;
    for (; i < E; i += stride) {
        int d = ld_idx(ei, (long long)E + i, is64);
        if ((unsigned)d < (unsigned)NNODES) atomicAdd(&deg[d], 1);
    }
}

__global__ void dinv_kernel(const int* __restrict__ deg, float* __restrict__ dinv, int N) {
    int i = blockIdx.x * blockDim.x + threadIdx.x;
    if (i < N) dinv[i] = rsqrtf((float)deg[i] + 1.0f);
}

__global__ void scatter_kernel(const float* __restrict__ H, const void* ei,
                               const int* __restrict__ flags,
                               const float* __restrict__ dinv,
                               float* __restrict__ agg, int E) {
    int is64 = flags[1];
    int lane = threadIdx.x & 63;
    int e = blockIdx.x * 4 + (threadIdx.x >> 6);
    if (e >= E) return;
    int s = ld_idx(ei, e, is64);
    int d = ld_idx(ei, (long long)E + e, is64);
    if ((unsigned)s >= (unsigned)NNODES || (unsigned)d >= (unsigned)NNODES) return;
    float nrm = dinv[s] * dinv[d];
    float v = H[(long long)s * 64 + lane] * nrm;
    atomicAdd(&agg[(long long)d * 64 + lane], v);
}

__global__ void relu_bias_kernel(float* __restrict__ H, const float* __restrict__ agg,
                                 const float* __restrict__ dinv, const void* b,
                                 const int* __restrict__ flags, int N) {
    int isf32 = flags[0];
    long long idx = (long long)blockIdx.x * blockDim.x + threadIdx.x;
    if (idx >= (long long)N * 64) return;
    int n = (int)(idx >> 6);
    int c = (int)(idx & 63);
    float dv = dinv[n];
    float v = agg[idx] + H[idx] * dv * dv + ld_f(b, c, isf32);
    H[idx] = v > 0.f ? v : 0.f;
}

__global__ void pool_fb_kernel(const float* __restrict__ agg, const float* __restrict__ Hg,
                               const float* __restrict__ dinv, const void* b,
                               const void* batch, const int* __restrict__ flags,
                               float* __restrict__ pooled, float* __restrict__ cnt, int N) {
    __shared__ float part[NG * 64];
    __shared__ float scnt[NG];
    int isf32 = flags[0];
    int b64   = flags[2];
    int tid = threadIdx.x;
    for (int i = tid; i < NG * 64; i += blockDim.x) part[i] = 0.f;
    if (tid < NG) scnt[tid] = 0.f;
    __syncthreads();
    int c = tid & 63;
    int sub = tid >> 6;
    float bc = ld_f(b, c, isf32);
    for (int n = blockIdx.x * 4 + sub; n < N; n += gridDim.x * 4) {
        int g = ld_idx(batch, n, b64);
        if ((unsigned)g >= (unsigned)NG) continue;
        float dv = dinv[n];
        float v = agg[(long long)n * 64 + c] + Hg[(long long)n * 64 + c] * dv * dv + bc;
        v = v > 0.f ? v : 0.f;
        atomicAdd(&part[g * 64 + c], v);
        if (c == 0) atomicAdd(&scnt[g], 1.0f);
    }
    __syncthreads();
    for (int i = tid; i < NG * 64; i += blockDim.x) {
        float v = part[i];
        if (v != 0.f) atomicAdd(&pooled[i], v);
    }
    if (tid < NG && scnt[tid] != 0.f) atomicAdd(&cnt[tid], scnt[tid]);
}

__global__ void zero_out_kernel(unsigned short* out, int n16) {
    int i = blockIdx.x * blockDim.x + threadIdx.x;
    if (i < n16) out[i] = 0;
}

extern "C" void kernel_launch(void* const* d_in, const int* in_sizes, int n_in,
                              void* d_out, int out_size, void* d_ws, size_t ws_size,
                              hipStream_t stream) {
    const void* x   = d_in[0];
    const void* ei  = d_in[1];   // [2, E] flat: src then dst
    const void* bat = d_in[2];
    const void* W1  = d_in[3];
    const void* b1  = d_in[4];
    const void* W2  = d_in[5];
    const void* b2  = d_in[6];
    const void* lw  = d_in[7];
    const void* lb  = d_in[8];

    const int N = NNODES, E = NEDGES;
    int* ws = (int*)d_ws;
    const int NT = (N + 63) / 64;    // gemm tiles

    // ---- CSR-path layout (words). staging aliases bufA (dead before GEMM1). ----
    const long long o_flags = 0;                          // 16
    const long long o_deg   = 16;                         // N (CSR path: scan sums live here)
    const long long o_dinv  = 16 + (long long)N;          // N
    const long long o_rs    = 16 + 2LL * N;               // N+1
    const long long o_bcnt  = 300032;                     // SCAN_M+1 = 50177
    const long long o_pool  = 350272;                     // NG*64
    const long long o_cnt   = o_pool + NG * 64;           // NG
    const long long o_csr   = 354432;                     // E
    const long long o_bufA  = o_csr + E;                  // N*64 words (bf16 uses half)
    const long long o_bufB  = o_bufA + (long long)N * 64; // N*64 words
    const size_t need_csr = (size_t)(o_bufB + (long long)N * 64) * 4;   // ~65.4 MB

    // ---- fallback layout ----
    const size_t need_fb = (size_t)(204800 + 2LL * N * 64) * 4;

    if (ws_size >= need_csr) {
        int*      flags   = ws + o_flags;
        int*      bsums   = ws + o_deg;       // SCAN_NB+1 words
        float*    dinv    = (float*)(ws + o_dinv);
        int*      rs      = ws + o_rs;
        int*      bcnt    = ws + o_bcnt;
        float*    pooled  = (float*)(ws + o_pool);
        float*    cnt     = (float*)(ws + o_cnt);
        int*      csr     = ws + o_csr;
        unsigned* staging = (unsigned*)(ws + o_bufA);     // alias: dead before GEMM1
        __hip_bfloat16* hA = (__hip_bfloat16*)(ws + o_bufA);
        __hip_bfloat16* hB = (__hip_bfloat16*)(ws + o_bufB);

        detect_kernel<<<1, 256, 0, stream>>>(x, ei, bat, flags);
        hipMemsetAsync(pooled, 0, (NG * 64 + NG) * sizeof(float), stream);

        // binned CSR build: no global atomics, no serial scans, packed 4B staging
        binA_count<<<PB, 256, 0, stream>>>(ei, flags, bcnt, E);
        scanP1<<<SCAN_NB, 1024, 0, stream>>>(bcnt, bsums);
        scanP2<<<1, 64, 0, stream>>>(bsums);
        scanP3<<<SCAN_NB, 1024, 0, stream>>>(bcnt, bsums);
        binA_write<<<PB, 256, 0, stream>>>(ei, flags, bcnt, staging, E);
        binB_all<<<NBUCK, 256, 0, stream>>>(staging, bcnt, rs, dinv, csr);

        // layer 1: gemm1 -> bf16 dinv*(x@W1); gather1 -> bf16 dinv*relu(...)
        gemm_tile<128, 0, 1><<<NT, 256, 0, stream>>>(x, W1, flags, dinv, hA, N);
        gather_v<<<(N + 3) / 4, 256, 0, stream>>>(hA, rs, csr, dinv, b1, flags, dinv, hB, N);
        // layer 2: gemm2 bf16 -> bf16; standalone gather (full occupancy) -> bf16 H
        gemm_tile<64, 2, 1><<<NT, 256, 0, stream>>>(hB, W2, flags, nullptr, hA, N);
        gather_v<<<(N + 3) / 4, 256, 0, stream>>>(hA, rs, csr, dinv, b2, flags, nullptr, hB, N);

        pool2_bf<<<512, 256, 0, stream>>>(hB, bat, flags, pooled, cnt, N);
        final_kernel<<<1, 64, 0, stream>>>(pooled, cnt, lw, lb, flags, d_out);
    } else if (ws_size >= need_fb) {
        int*   flags  = ws;
        int*   deg    = ws + 16;
        float* dinv   = (float*)(ws + 16 + N);
        float* pooled = (float*)(ws + 16 + 2LL * N);
        float* cnt    = pooled + NG * 64;
        float* bufA   = (float*)(ws + 204800);
        float* bufB   = bufA + (long long)N * 64;

        detect_kernel<<<1, 256, 0, stream>>>(x, ei, bat, flags);
        hipMemsetAsync(deg, 0, N * sizeof(int), stream);
        hipMemsetAsync(pooled, 0, (NG * 64 + NG) * sizeof(float), stream);

        count_kernel<<<2048, 256, 0, stream>>>(ei, flags, deg, E);
        dinv_kernel<<<(N + 255) / 256, 256, 0, stream>>>(deg, dinv, N);

        gemm_tile<128, 0, 0><<<NT, 256, 0, stream>>>(x, W1, flags, nullptr, bufA, N);
        hipMemsetAsync(bufB, 0, (size_t)N * 64 * sizeof(float), stream);
        scatter_kernel<<<(E + 3) / 4, 256, 0, stream>>>(bufA, ei, flags, dinv, bufB, E);
        relu_bias_kernel<<<((long long)N * 64 + 255) / 256, 256, 0, stream>>>(bufA, bufB, dinv, b1, flags, N);

        gemm_tile<64, 1, 0><<<NT, 256, 0, stream>>>(bufA, W2, flags, nullptr, bufB, N);
        hipMemsetAsync(bufA, 0, (size_t)N * 64 * sizeof(float), stream);
        scatter_kernel<<<(E + 3) / 4, 256, 0, stream>>>(bufB, ei, flags, dinv, bufA, E);

        pool_fb_kernel<<<512, 256, 0, stream>>>(bufA, bufB, dinv, b2, bat, flags, pooled, cnt, N);
        final_kernel<<<1, 64, 0, stream>>>(pooled, cnt, lw, lb, flags, d_out);
    } else {
        zero_out_kernel<<<(out_size * 2 + 255) / 256, 256, 0, stream>>>(
            (unsigned short*)d_out, out_size);
    }
}

// Round 12
// 486.274 us; speedup vs baseline: 1.5952x; 1.1529x over previous
//
#include <hip/hip_runtime.h>
#include <hip/hip_bf16.h>

#define NNODES 100000
#define NEDGES 3200000
#define NG     64
#define NBUCK  196          // ceil(NNODES/512) buckets of 512 dst nodes
#define PB     256          // phase-A partition blocks
#define SCAN_M (PB * NBUCK) // 50176
#define SCAN_NB ((SCAN_M + 1023) / 1024)   // 49

typedef __attribute__((ext_vector_type(4))) short short4v;
typedef __attribute__((ext_vector_type(8))) short short8v;
typedef __attribute__((ext_vector_type(4))) float ffrag;

// ---------- dtype-flexible loads (flags are wave-uniform) ----------
__device__ __forceinline__ int ld_idx(const void* p, long long i, int is64) {
    if (is64) return (int)((const long long*)p)[i];
    return ((const int*)p)[i];
}
__device__ __forceinline__ float ld_f(const void* p, long long i, int isf32) {
    if (isf32) return ((const float*)p)[i];
    return __bfloat162float(((const __hip_bfloat16*)p)[i]);
}
__device__ __forceinline__ float bfbits(unsigned b) {
    return __uint_as_float(b << 16);
}
__device__ __forceinline__ unsigned short bf16b(float v) {
    __hip_bfloat16 h = __float2bfloat16(v);
    return *(unsigned short*)&h;
}

// ---------- runtime dtype detection (parallel, 256 threads) ----------
__global__ void detect_kernel(const void* x, const void* ei, const void* bat, int* flags) {
    __shared__ int f[3];
    int t = threadIdx.x;
    if (t < 3) f[t] = 0;
    __syncthreads();
    const unsigned short* u = (const unsigned short*)x;
    int e = (u[t] >> 7) & 0xFF;
    if (e >= 0x90) atomicOr(&f[0], 1);                 // fp32-reinterpret signature
    const unsigned* w = (const unsigned*)ei;
    if (w[2 * t + 1] != 0u) atomicOr(&f[1], 1);        // odd word nonzero -> int32
    const unsigned* bw = (const unsigned*)bat;
    if (bw[50001 + 2 * t] != 0u) atomicOr(&f[2], 1);   // mid-array odd words
    __syncthreads();
    if (t == 0) { flags[0] = f[0]; flags[1] = !f[1]; flags[2] = !f[2]; }
}

// ---------- phase A1: per-(bucket,block) edge counts (LDS only) ----------
__global__ void binA_count(const void* ei, const int* __restrict__ flags,
                           int* __restrict__ bcnt, int E) {
    __shared__ int cnt[NBUCK];
    int is64 = flags[1];
    for (int i = threadIdx.x; i < NBUCK; i += 256) cnt[i] = 0;
    __syncthreads();
    const int chunk = (E + PB - 1) / PB;
    int beg = blockIdx.x * chunk, end = min(E, beg + chunk);
    for (int i = beg + threadIdx.x; i < end; i += 256) {
        int s = ld_idx(ei, i, is64);
        int d = ld_idx(ei, (long long)E + i, is64);
        if ((unsigned)s < (unsigned)NNODES && (unsigned)d < (unsigned)NNODES)
            atomicAdd(&cnt[d >> 9], 1);
    }
    __syncthreads();
    for (int i = threadIdx.x; i < NBUCK; i += 256)
        bcnt[i * PB + blockIdx.x] = cnt[i];     // bucket-major for scan
}

// ---------- parallel 3-phase exclusive scan over bcnt[SCAN_M] ----------
__global__ void scanP1(int* __restrict__ a, int* __restrict__ sums) {
    __shared__ int ls[1024];
    int t = threadIdx.x;
    int i = blockIdx.x * 1024 + t;
    int v = (i < SCAN_M) ? a[i] : 0;
    ls[t] = v;
    __syncthreads();
    for (int off = 1; off < 1024; off <<= 1) {
        int p = (t >= off) ? ls[t - off] : 0;
        __syncthreads();
        ls[t] += p;
        __syncthreads();
    }
    if (i < SCAN_M) a[i] = ls[t] - v;           // exclusive within block
    if (t == 1023) sums[blockIdx.x] = ls[1023]; // block total
}

__global__ void scanP2(int* __restrict__ sums) {
    __shared__ int ls[SCAN_NB];
    int t = threadIdx.x;
    if (t < SCAN_NB) ls[t] = sums[t];
    __syncthreads();
    if (t == 0) {
        int run = 0;
        for (int i = 0; i < SCAN_NB; ++i) { int c = ls[i]; ls[i] = run; run += c; }
        sums[SCAN_NB] = run;                    // grand total
    }
    __syncthreads();
    if (t < SCAN_NB) sums[t] = ls[t];
}

__global__ void scanP3(int* __restrict__ a, const int* __restrict__ sums) {
    int i = blockIdx.x * 1024 + threadIdx.x;
    if (i < SCAN_M) a[i] += sums[blockIdx.x];
    if (i == 0) a[SCAN_M] = sums[SCAN_NB];      // bcnt[M] = total
}

// ---------- phase A3: partition edges into bucket-ordered packed staging ----------
// pack: s (17 bits) | (d - bucket_lo) << 17  (9 bits) -> 4 B per edge
__global__ void binA_write(const void* ei, const int* __restrict__ flags,
                           const int* __restrict__ bcnt, unsigned* __restrict__ staging, int E) {
    __shared__ int cur[NBUCK];
    int is64 = flags[1];
    for (int i = threadIdx.x; i < NBUCK; i += 256) cur[i] = bcnt[i * PB + blockIdx.x];
    __syncthreads();
    const int chunk = (E + PB - 1) / PB;
    int beg = blockIdx.x * chunk, end = min(E, beg + chunk);
    for (int i = beg + threadIdx.x; i < end; i += 256) {
        int s = ld_idx(ei, i, is64);
        int d = ld_idx(ei, (long long)E + i, is64);
        if ((unsigned)s < (unsigned)NNODES && (unsigned)d < (unsigned)NNODES) {
            int pos = atomicAdd(&cur[d >> 9], 1);
            staging[pos] = (unsigned)s | ((unsigned)(d & 511) << 17);
        }
    }
}

// ---------- phase B (fused): per-bucket degrees -> rs + dinv + CSR fill ----------
__global__ void binB_all(const unsigned* __restrict__ staging, const int* __restrict__ bcnt,
                         int* __restrict__ rs, float* __restrict__ dinv,
                         int* __restrict__ csr) {
    __shared__ int dcnt[512];
    __shared__ int ls[256];
    int b = blockIdx.x;
    int lo = b << 9;
    int t = threadIdx.x;
    for (int i = t; i < 512; i += 256) dcnt[i] = 0;
    __syncthreads();
    int beg = bcnt[b * PB], end = bcnt[(b + 1) * PB];
    for (int i = beg + t; i < end; i += 256)
        atomicAdd(&dcnt[staging[i] >> 17], 1);
    __syncthreads();
    int a  = dcnt[2 * t];
    int b2 = dcnt[2 * t + 1];
    int csum = a + b2;
    ls[t] = csum;
    __syncthreads();
    for (int off = 1; off < 256; off <<= 1) {
        int p = (t >= off) ? ls[t - off] : 0;
        __syncthreads();
        ls[t] += p;
        __syncthreads();
    }
    int pref = ls[t] - csum;
    int n0 = lo + 2 * t, n1 = lo + 2 * t + 1;
    if (n0 < NNODES) { rs[n0] = beg + pref;     dinv[n0] = rsqrtf((float)a + 1.0f); }
    if (n1 < NNODES) { rs[n1] = beg + pref + a; dinv[n1] = rsqrtf((float)b2 + 1.0f); }
    if (b == NBUCK - 1 && t == 0) rs[NNODES] = bcnt[SCAN_M];
    __syncthreads();
    dcnt[2 * t]     = beg + pref;               // cursors
    dcnt[2 * t + 1] = beg + pref + a;
    __syncthreads();
    for (int i = beg + t; i < end; i += 256) {  // staging chunk L2-hot from pass 1
        unsigned u = staging[i];
        int pos = atomicAdd(&dcnt[u >> 17], 1);
        csr[pos] = (int)(u & 0x1FFFFu);
    }
}

// ---------- MFMA GEMM: bf16 X,W tiles in LDS (padded), 16x16x32 bf16 MFMA ----------
// XMODE 0: X has detected dtype (bf16 usual; fp32 converted in staging); 2: bf16 workspace.
// Layouts (m89/m120 verified): A[m=lane&15][k=quad*8+j]; B[k=quad*8+j][n=lane&15];
// C/D row=quad*4+reg, col=lane&15.
template <int K, int XMODE>
__global__ __launch_bounds__(256)
void gemm_mfma(const void* __restrict__ X, const void* __restrict__ W,
               const int* __restrict__ flags, const float* __restrict__ dscale,
               __hip_bfloat16* __restrict__ Out, int N) {
    const int S = K + 4;                 // +8B pad: frag b64 reads land on <=4-way banks
    __shared__ unsigned short lsWt[64 * S];   // [c][k] bf16 (W transposed)
    __shared__ unsigned short lsX[64 * S];    // [r][k] bf16
    int isf32 = flags[0];
    // stage W transposed (once per block): coalesced read, scattered LDS write
    for (int i = threadIdx.x; i < K * 64; i += 256) {
        int k = i >> 6, c = i & 63;
        unsigned short v = isf32 ? bf16b(((const float*)W)[i])
                                 : ((const unsigned short*)W)[i];
        lsWt[c * S + k] = v;
    }

    int lane = threadIdx.x & 63;
    int wv   = threadIdx.x >> 6;        // wave owns rows [wv*16, wv*16+16)
    int m    = lane & 15;
    int quad = lane >> 4;
    int ntiles = (N + 63) >> 6;

    for (int t = blockIdx.x; t < ntiles; t += gridDim.x) {
        int row0 = t << 6;
        int nrows = min(64, N - row0);
        int nchunk = (nrows * K) >> 2;  // 4 ushorts per chunk
        __syncthreads();                // prev readers done (covers lsWt on 1st iter)
        if (XMODE == 0 && isf32) {
            const float4* Xb = (const float4*)((const float*)X + (long long)row0 * K);
            for (int i = threadIdx.x; i < nchunk; i += 256) {
                int r = (i << 2) / K;
                int k = (i << 2) & (K - 1);
                float4 v = Xb[i];
                uint2 o;
                o.x = (unsigned)bf16b(v.x) | ((unsigned)bf16b(v.y) << 16);
                o.y = (unsigned)bf16b(v.z) | ((unsigned)bf16b(v.w) << 16);
                *(uint2*)&lsX[r * S + k] = o;
            }
        } else {
            const uint2* Xb = (const uint2*)((const unsigned short*)X + (long long)row0 * K);
            for (int i = threadIdx.x; i < nchunk; i += 256) {
                int r = (i << 2) / K;
                int k = (i << 2) & (K - 1);
                *(uint2*)&lsX[r * S + k] = Xb[i];
            }
        }
        __syncthreads();

        int rbase = wv * 16;
        ffrag acc0 = {0.f, 0.f, 0.f, 0.f};
        ffrag acc1 = {0.f, 0.f, 0.f, 0.f};
        ffrag acc2 = {0.f, 0.f, 0.f, 0.f};
        ffrag acc3 = {0.f, 0.f, 0.f, 0.f};
        int abase = (rbase + m) * S + quad * 8;
#pragma unroll
        for (int ks = 0; ks < K; ks += 32) {
            short4v al = *(const short4v*)&lsX[abase + ks];
            short4v ah = *(const short4v*)&lsX[abase + ks + 4];
            short8v a = __builtin_shufflevector(al, ah, 0, 1, 2, 3, 4, 5, 6, 7);
#pragma unroll
            for (int ct = 0; ct < 4; ++ct) {
                int boff = (ct * 16 + m) * S + quad * 8 + ks;
                short4v bl = *(const short4v*)&lsWt[boff];
                short4v bh = *(const short4v*)&lsWt[boff + 4];
                short8v b = __builtin_shufflevector(bl, bh, 0, 1, 2, 3, 4, 5, 6, 7);
                if (ct == 0) acc0 = __builtin_amdgcn_mfma_f32_16x16x32_bf16(a, b, acc0, 0, 0, 0);
                if (ct == 1) acc1 = __builtin_amdgcn_mfma_f32_16x16x32_bf16(a, b, acc1, 0, 0, 0);
                if (ct == 2) acc2 = __builtin_amdgcn_mfma_f32_16x16x32_bf16(a, b, acc2, 0, 0, 0);
                if (ct == 3) acc3 = __builtin_amdgcn_mfma_f32_16x16x32_bf16(a, b, acc3, 0, 0, 0);
            }
        }
        long long ob = (long long)row0 * 64;
#pragma unroll
        for (int r = 0; r < 4; ++r) {
            int row = rbase + quad * 4 + r;
            if (row < nrows) {
                float ds = dscale ? dscale[row0 + row] : 1.f;
                long long rb = ob + (long long)row * 64 + m;
                Out[rb]      = __float2bfloat16(acc0[r] * ds);
                Out[rb + 16] = __float2bfloat16(acc1[r] * ds);
                Out[rb + 32] = __float2bfloat16(acc2[r] * ds);
                Out[rb + 48] = __float2bfloat16(acc3[r] * ds);
            }
        }
    }
}

// ---------- fp32 VALU GEMM (fallback path only; round-7 proven) ----------
template <int K, int XMODE>
__global__ __launch_bounds__(256)
void gemm_tile(const void* __restrict__ X, const void* __restrict__ W,
               const int* __restrict__ flags, const float* __restrict__ dscale,
               float* __restrict__ Out, int N) {
    __shared__ float lsW[K * 64];
    __shared__ float lsX[64 * K];
    int isf32 = flags[0];
    for (int i = threadIdx.x; i < K * 64; i += 256) lsW[i] = ld_f(W, i, isf32);
    int c  = threadIdx.x & 63;
    int wv = threadIdx.x >> 6;
    int ntiles = (N + 63) >> 6;
    for (int t = blockIdx.x; t < ntiles; t += gridDim.x) {
        int row0 = t << 6;
        int nrows = min(64, N - row0);
        int total = nrows * K;
        __syncthreads();
        if (XMODE == 1 || (XMODE == 0 && isf32)) {
            const float* Xb = (const float*)X + (long long)row0 * K;
            for (int i = threadIdx.x; i < total; i += 256) lsX[i] = Xb[i];
        } else {
            const unsigned short* Xb = (const unsigned short*)X + (long long)row0 * K;
            for (int i = threadIdx.x; i < total; i += 256) lsX[i] = bfbits((unsigned)Xb[i]);
        }
        __syncthreads();
        int rbase = wv * 16;
        float acc[16];
#pragma unroll
        for (int r = 0; r < 16; ++r) acc[r] = 0.f;
#pragma unroll 1
        for (int kc = 0; kc < K; kc += 8) {
            float w0 = lsW[(kc + 0) * 64 + c], w1 = lsW[(kc + 1) * 64 + c];
            float w2 = lsW[(kc + 2) * 64 + c], w3 = lsW[(kc + 3) * 64 + c];
            float w4 = lsW[(kc + 4) * 64 + c], w5 = lsW[(kc + 5) * 64 + c];
            float w6 = lsW[(kc + 6) * 64 + c], w7 = lsW[(kc + 7) * 64 + c];
#pragma unroll
            for (int r = 0; r < 16; ++r) {
                const float4* xp = (const float4*)&lsX[(rbase + r) * K + kc];
                float4 xa = xp[0], xb = xp[1];
                acc[r] += xa.x * w0 + xa.y * w1 + xa.z * w2 + xa.w * w3
                        + xb.x * w4 + xb.y * w5 + xb.z * w6 + xb.w * w7;
            }
        }
        long long ob = (long long)row0 * 64;
#pragma unroll
        for (int r = 0; r < 16; ++r) {
            int rr = rbase + r;
            if (rr < nrows) {
                float v = acc[r];
                if (dscale) v *= dscale[row0 + rr];
                Out[ob + (long long)rr * 64 + c] = v;
            }
        }
    }
}

// ---------- vectorized CSR gather (round-11 proven) ----------
__global__ __launch_bounds__(256)
void gather_v(const __hip_bfloat16* __restrict__ Hs,
              const int* __restrict__ row_start,
              const int* __restrict__ csr_src,
              const float* __restrict__ dinv,
              const void* bias, const int* __restrict__ flags,
              const float* __restrict__ out_scale,
              __hip_bfloat16* __restrict__ Hout, int N) {
    int isf32 = flags[0];
    int lane = threadIdx.x & 63;
    int e = lane >> 3;
    int f = lane & 7;
    int n = blockIdx.x * 4 + (threadIdx.x >> 6);
    if (n >= N) return;
    int beg = row_start[n], end = row_start[n + 1];

    float acc[8];
#pragma unroll
    for (int j = 0; j < 8; ++j) acc[j] = 0.f;

    for (int i = beg; i < end; i += 8) {
        int idx = i + e;
        if (idx < end) {
            int s = csr_src[idx];
            const uint4* hp = (const uint4*)(Hs + ((long long)s << 6)) + f;
            uint4 u = *hp;
            acc[0] += bfbits(u.x & 0xffffu); acc[1] += bfbits(u.x >> 16);
            acc[2] += bfbits(u.y & 0xffffu); acc[3] += bfbits(u.y >> 16);
            acc[4] += bfbits(u.z & 0xffffu); acc[5] += bfbits(u.z >> 16);
            acc[6] += bfbits(u.w & 0xffffu); acc[7] += bfbits(u.w >> 16);
        }
    }
#pragma unroll
    for (int j = 0; j < 8; ++j) {
        acc[j] += __shfl_xor(acc[j], 8);
        acc[j] += __shfl_xor(acc[j], 16);
        acc[j] += __shfl_xor(acc[j], 32);
    }
    const uint4* sp = (const uint4*)(Hs + ((long long)n << 6)) + f;
    uint4 su = *sp;
    float self[8] = { bfbits(su.x & 0xffffu), bfbits(su.x >> 16),
                      bfbits(su.y & 0xffffu), bfbits(su.y >> 16),
                      bfbits(su.z & 0xffffu), bfbits(su.z >> 16),
                      bfbits(su.w & 0xffffu), bfbits(su.w >> 16) };
    float dn = dinv[n];
    float osc = out_scale ? out_scale[n] : 1.f;
    if (e == 0) {
        unsigned short h[8];
#pragma unroll
        for (int j = 0; j < 8; ++j) {
            float v = (acc[j] + self[j]) * dn + ld_f(bias, 8 * f + j, isf32);
            float r = v > 0.f ? v : 0.f;
            h[j] = bf16b(r * osc);
        }
        uint4 o;
        o.x = (unsigned)h[0] | ((unsigned)h[1] << 16);
        o.y = (unsigned)h[2] | ((unsigned)h[3] << 16);
        o.z = (unsigned)h[4] | ((unsigned)h[5] << 16);
        o.w = (unsigned)h[6] | ((unsigned)h[7] << 16);
        *((uint4*)(Hout + ((long long)n << 6)) + f) = o;
    }
}

// ---------- pooling over bf16 H ----------
__global__ void pool2_bf(const __hip_bfloat16* __restrict__ H, const void* batch,
                         const int* __restrict__ flags,
                         float* __restrict__ pooled, float* __restrict__ cnt, int N) {
    __shared__ float part[NG * 64];
    __shared__ float scnt[NG];
    int b64 = flags[2];
    int tid = threadIdx.x;
    for (int i = tid; i < NG * 64; i += 256) part[i] = 0.f;
    if (tid < NG) scnt[tid] = 0.f;
    __syncthreads();
    int c = tid & 63;
    int sub = tid >> 6;
    for (int n = blockIdx.x * 4 + sub; n < N; n += gridDim.x * 4) {
        int g = ld_idx(batch, n, b64);
        if ((unsigned)g >= (unsigned)NG) continue;
        atomicAdd(&part[g * 64 + c], __bfloat162float(H[(long long)n * 64 + c]));
        if (c == 0) atomicAdd(&scnt[g], 1.0f);
    }
    __syncthreads();
    for (int i = tid; i < NG * 64; i += 256) {
        float v = part[i];
        if (v != 0.f) atomicAdd(&pooled[i], v);
    }
    if (tid < NG && scnt[tid] != 0.f) atomicAdd(&cnt[tid], scnt[tid]);
}

// ---------- final ----------
__global__ void final_kernel(const float* __restrict__ pooled, const float* __restrict__ cnt,
                             const void* lw, const void* lb,
                             const int* __restrict__ flags, void* out) {
    int isf32 = flags[0];
    int g = threadIdx.x;
    if (g >= NG) return;
    float inv = 1.0f / fmaxf(cnt[g], 1.0f);
    float logits[10];
    for (int c = 0; c < 10; ++c) logits[c] = ld_f(lb, c, isf32);
    for (int k = 0; k < 64; ++k) {
        float m = pooled[g * 64 + k] * inv;
        for (int c = 0; c < 10; ++c)
            logits[c] += m * ld_f(lw, k * 10 + c, isf32);
    }
    float mx = logits[0];
    for (int c = 1; c < 10; ++c) mx = fmaxf(mx, logits[c]);
    float se = 0.f;
    for (int c = 0; c < 10; ++c) se += __expf(logits[c] - mx);
    float lse = mx + __logf(se);
    if (isf32) {
        float* o = (float*)out;
        for (int c = 0; c < 10; ++c) o[g * 10 + c] = logits[c] - lse;
    } else {
        __hip_bfloat16* o = (__hip_bfloat16*)out;
        for (int c = 0; c < 10; ++c) o[g * 10 + c] = __float2bfloat16(logits[c] - lse);
    }
}

// ---------- fallback pipeline kernels (round-2 proven, atomic scatter, fp32) ----------
__global__ void count_kernel(const void* ei, const int* __restrict__ flags,
                             int* __restrict__ deg, int E) {
    int is64 = flags[1];
    int i = blockIdx.x * blockDim.x + threadIdx.x;
    int stride = gridDim.x * blockDim.x;
    for (; i < E; i += stride) {
        int d = ld_idx(ei, (long long)E + i, is64);
        if ((unsigned)d < (unsigned)NNODES) atomicAdd(&deg[d], 1);
    }
}

__global__ void dinv_kernel(const int* __restrict__ deg, float* __restrict__ dinv, int N) {
    int i = blockIdx.x * blockDim.x + threadIdx.x;
    if (i < N) dinv[i] = rsqrtf((float)deg[i] + 1.0f);
}

__global__ void scatter_kernel(const float* __restrict__ H, const void* ei,
                               const int* __restrict__ flags,
                               const float* __restrict__ dinv,
                               float* __restrict__ agg, int E) {
    int is64 = flags[1];
    int lane = threadIdx.x & 63;
    int e = blockIdx.x * 4 + (threadIdx.x >> 6);
    if (e >= E) return;
    int s = ld_idx(ei, e, is64);
    int d = ld_idx(ei, (long long)E + e, is64);
    if ((unsigned)s >= (unsigned)NNODES || (unsigned)d >= (unsigned)NNODES) return;
    float nrm = dinv[s] * dinv[d];
    float v = H[(long long)s * 64 + lane] * nrm;
    atomicAdd(&agg[(long long)d * 64 + lane], v);
}

__global__ void relu_bias_kernel(float* __restrict__ H, const float* __restrict__ agg,
                                 const float* __restrict__ dinv, const void* b,
                                 const int* __restrict__ flags, int N) {
    int isf32 = flags[0];
    long long idx = (long long)blockIdx.x * blockDim.x + threadIdx.x;
    if (idx >= (long long)N * 64) return;
    int n = (int)(idx >> 6);
    int c = (int)(idx & 63);
    float dv = dinv[n];
    float v = agg[idx] + H[idx] * dv * dv + ld_f(b, c, isf32);
    H[idx] = v > 0.f ? v : 0.f;
}

__global__ void pool_fb_kernel(const float* __restrict__ agg, const float* __restrict__ Hg,
                               const float* __restrict__ dinv, const void* b,
                               const void* batch, const int* __restrict__ flags,
                               float* __restrict__ pooled, float* __restrict__ cnt, int N) {
    __shared__ float part[NG * 64];
    __shared__ float scnt[NG];
    int isf32 = flags[0];
    int b64   = flags[2];
    int tid = threadIdx.x;
    for (int i = tid; i < NG * 64; i += blockDim.x) part[i] = 0.f;
    if (tid < NG) scnt[tid] = 0.f;
    __syncthreads();
    int c = tid & 63;
    int sub = tid >> 6;
    float bc = ld_f(b, c, isf32);
    for (int n = blockIdx.x * 4 + sub; n < N; n += gridDim.x * 4) {
        int g = ld_idx(batch, n, b64);
        if ((unsigned)g >= (unsigned)NG) continue;
        float dv = dinv[n];
        float v = agg[(long long)n * 64 + c] + Hg[(long long)n * 64 + c] * dv * dv + bc;
        v = v > 0.f ? v : 0.f;
        atomicAdd(&part[g * 64 + c], v);
        if (c == 0) atomicAdd(&scnt[g], 1.0f);
    }
    __syncthreads();
    for (int i = tid; i < NG * 64; i += blockDim.x) {
        float v = part[i];
        if (v != 0.f) atomicAdd(&pooled[i], v);
    }
    if (tid < NG && scnt[tid] != 0.f) atomicAdd(&cnt[tid], scnt[tid]);
}

__global__ void zero_out_kernel(unsigned short* out, int n16) {
    int i = blockIdx.x * blockDim.x + threadIdx.x;
    if (i < n16) out[i] = 0;
}

extern "C" void kernel_launch(void* const* d_in, const int* in_sizes, int n_in,
                              void* d_out, int out_size, void* d_ws, size_t ws_size,
                              hipStream_t stream) {
    const void* x   = d_in[0];
    const void* ei  = d_in[1];   // [2, E] flat: src then dst
    const void* bat = d_in[2];
    const void* W1  = d_in[3];
    const void* b1  = d_in[4];
    const void* W2  = d_in[5];
    const void* b2  = d_in[6];
    const void* lw  = d_in[7];
    const void* lb  = d_in[8];

    const int N = NNODES, E = NEDGES;
    int* ws = (int*)d_ws;
    const int NT = (N + 63) / 64;    // gemm tiles

    // ---- CSR-path layout (words). staging aliases bufA (dead before GEMM1). ----
    const long long o_flags = 0;                          // 16
    const long long o_deg   = 16;                         // N (CSR path: scan sums live here)
    const long long o_dinv  = 16 + (long long)N;          // N
    const long long o_rs    = 16 + 2LL * N;               // N+1
    const long long o_bcnt  = 300032;                     // SCAN_M+1 = 50177
    const long long o_pool  = 350272;                     // NG*64
    const long long o_cnt   = o_pool + NG * 64;           // NG
    const long long o_csr   = 354432;                     // E
    const long long o_bufA  = o_csr + E;                  // N*64 words (bf16 uses half)
    const long long o_bufB  = o_bufA + (long long)N * 64; // N*64 words
    const size_t need_csr = (size_t)(o_bufB + (long long)N * 64) * 4;   // ~65.4 MB

    // ---- fallback layout ----
    const size_t need_fb = (size_t)(204800 + 2LL * N * 64) * 4;

    if (ws_size >= need_csr) {
        int*      flags   = ws + o_flags;
        int*      bsums   = ws + o_deg;       // SCAN_NB+1 words
        float*    dinv    = (float*)(ws + o_dinv);
        int*      rs      = ws + o_rs;
        int*      bcnt    = ws + o_bcnt;
        float*    pooled  = (float*)(ws + o_pool);
        float*    cnt     = (float*)(ws + o_cnt);
        int*      csr     = ws + o_csr;
        unsigned* staging = (unsigned*)(ws + o_bufA);     // alias: dead before GEMM1
        __hip_bfloat16* hA = (__hip_bfloat16*)(ws + o_bufA);
        __hip_bfloat16* hB = (__hip_bfloat16*)(ws + o_bufB);

        detect_kernel<<<1, 256, 0, stream>>>(x, ei, bat, flags);
        hipMemsetAsync(pooled, 0, (NG * 64 + NG) * sizeof(float), stream);

        // binned CSR build: no global atomics, no serial scans, packed 4B staging
        binA_count<<<PB, 256, 0, stream>>>(ei, flags, bcnt, E);
        scanP1<<<SCAN_NB, 1024, 0, stream>>>(bcnt, bsums);
        scanP2<<<1, 64, 0, stream>>>(bsums);
        scanP3<<<SCAN_NB, 1024, 0, stream>>>(bcnt, bsums);
        binA_write<<<PB, 256, 0, stream>>>(ei, flags, bcnt, staging, E);
        binB_all<<<NBUCK, 256, 0, stream>>>(staging, bcnt, rs, dinv, csr);

        // layer 1: MFMA gemm1 -> bf16 dinv*(x@W1); gather1 -> bf16 dinv*relu(...)
        gemm_mfma<128, 0><<<NT, 256, 0, stream>>>(x, W1, flags, dinv, hA, N);
        gather_v<<<(N + 3) / 4, 256, 0, stream>>>(hA, rs, csr, dinv, b1, flags, dinv, hB, N);
        // layer 2: MFMA gemm2 bf16 -> bf16; standalone gather -> bf16 H
        gemm_mfma<64, 2><<<NT, 256, 0, stream>>>(hB, W2, flags, nullptr, hA, N);
        gather_v<<<(N + 3) / 4, 256, 0, stream>>>(hA, rs, csr, dinv, b2, flags, nullptr, hB, N);

        pool2_bf<<<512, 256, 0, stream>>>(hB, bat, flags, pooled, cnt, N);
        final_kernel<<<1, 64, 0, stream>>>(pooled, cnt, lw, lb, flags, d_out);
    } else if (ws_size >= need_fb) {
        int*   flags  = ws;
        int*   deg    = ws + 16;
        float* dinv   = (float*)(ws + 16 + N);
        float* pooled = (float*)(ws + 16 + 2LL * N);
        float* cnt    = pooled + NG * 64;
        float* bufA   = (float*)(ws + 204800);
        float* bufB   = bufA + (long long)N * 64;

        detect_kernel<<<1, 256, 0, stream>>>(x, ei, bat, flags);
        hipMemsetAsync(deg, 0, N * sizeof(int), stream);
        hipMemsetAsync(pooled, 0, (NG * 64 + NG) * sizeof(float), stream);

        count_kernel<<<2048, 256, 0, stream>>>(ei, flags, deg, E);
        dinv_kernel<<<(N + 255) / 256, 256, 0, stream>>>(deg, dinv, N);

        gemm_tile<128, 0><<<NT, 256, 0, stream>>>(x, W1, flags, nullptr, bufA, N);
        hipMemsetAsync(bufB, 0, (size_t)N * 64 * sizeof(float), stream);
        scatter_kernel<<<(E + 3) / 4, 256, 0, stream>>>(bufA, ei, flags, dinv, bufB, E);
        relu_bias_kernel<<<((long long)N * 64 + 255) / 256, 256, 0, stream>>>(bufA, bufB, dinv, b1, flags, N);

        gemm_tile<64, 1><<<NT, 256, 0, stream>>>(bufA, W2, flags, nullptr, bufB, N);
        hipMemsetAsync(bufA, 0, (size_t)N * 64 * sizeof(float), stream);
        scatter_kernel<<<(E + 3) / 4, 256, 0, stream>>>(bufB, ei, flags, dinv, bufA, E);

        pool_fb_kernel<<<512, 256, 0, stream>>>(bufA, bufB, dinv, b2, bat, flags, pooled, cnt, N);
        final_kernel<<<1, 64, 0, stream>>>(pooled, cnt, lw, lb, flags, d_out);
    } else {
        zero_out_kernel<<<(out_size * 2 + 255) / 256, 256, 0, stream>>>(
            (unsigned short*)d_out, out_size);
    }
}